// Round 8
// baseline (4974.897 us; speedup 1.0000x reference)
//
#include <hip/hip_runtime.h>
#include <hip/hip_bf16.h>

#define K_TAPS 27
#define DCH 64
#define BN_EPS 1e-5f
#define SCAN_CHUNK 4096

typedef float f32x4 __attribute__((ext_vector_type(4)));
typedef float f32x2 __attribute__((ext_vector_type(2)));

// packed fp32 FMA: a += f * w  (2 lanes-of-2 per instruction)
#define PKFMA(a, f, w) \
    asm("v_pk_fma_f32 %0, %1, %2, %0" : "+v"(a) : "v"(f), "v"(w))

// ---------------------------------------------------------------------------
// CSR build: histogram over buckets b = orow*27 + k
// ---------------------------------------------------------------------------
__global__ __launch_bounds__(256)
void hist_kernel(const int* __restrict__ pout, int P, int* __restrict__ counts)
{
    const int k = blockIdx.y;
    const int p = blockIdx.x * 256 + threadIdx.x;
    if (p < P) {
        const int r = pout[(size_t)k * P + p];
        atomicAdd(&counts[r * K_TAPS + k], 1);
    }
}

__global__ __launch_bounds__(256)
void scan_sum_kernel(const int* __restrict__ counts, int n, int* __restrict__ partials)
{
    __shared__ int sm[256];
    const int base = blockIdx.x * SCAN_CHUNK;
    int s = 0;
#pragma unroll
    for (int j = 0; j < 16; ++j) {
        const int i = base + j * 256 + threadIdx.x;
        if (i < n) s += counts[i];
    }
    sm[threadIdx.x] = s;
    __syncthreads();
    for (int off = 128; off > 0; off >>= 1) {
        if (threadIdx.x < off) sm[threadIdx.x] += sm[threadIdx.x + off];
        __syncthreads();
    }
    if (threadIdx.x == 0) partials[blockIdx.x] = sm[0];
}

__global__ __launch_bounds__(512)
void scan_partials_kernel(int* __restrict__ partials, int n)
{
    __shared__ int sm[512];
    const int t = threadIdx.x;
    const int v = (t < n) ? partials[t] : 0;
    sm[t] = v;
    __syncthreads();
    for (int off = 1; off < 512; off <<= 1) {
        int tv = 0;
        if (t >= off) tv = sm[t - off];
        __syncthreads();
        if (t >= off) sm[t] += tv;
        __syncthreads();
    }
    if (t < n) partials[t] = sm[t] - v;  // exclusive
}

__global__ __launch_bounds__(256)
void scan_write_kernel(const int* __restrict__ counts, int n,
                       const int* __restrict__ chunkoff, int* __restrict__ S)
{
    __shared__ int sm[256];
    const int base = blockIdx.x * SCAN_CHUNK + threadIdx.x * 16;
    int v[16];
    int s = 0;
#pragma unroll
    for (int j = 0; j < 16; ++j) {
        const int i = base + j;
        v[j] = (i < n) ? counts[i] : 0;
        s += v[j];
    }
    sm[threadIdx.x] = s;
    __syncthreads();
    for (int off = 1; off < 256; off <<= 1) {
        int tv = 0;
        if (threadIdx.x >= off) tv = sm[threadIdx.x - off];
        __syncthreads();
        if (threadIdx.x >= off) sm[threadIdx.x] += tv;
        __syncthreads();
    }
    int run = chunkoff[blockIdx.x] + sm[threadIdx.x] - s;  // exclusive base
#pragma unroll
    for (int j = 0; j < 16; ++j) {
        const int i = base + j;
        if (i < n) S[i + 1] = run;
        run += v[j];
    }
    if (blockIdx.x == 0 && threadIdx.x == 0) S[0] = 0;
}

__global__ __launch_bounds__(256)
void fill_kernel(const int* __restrict__ pin, const int* __restrict__ pout, int P,
                 int* __restrict__ S, int* __restrict__ E)
{
    const int k = blockIdx.y;
    const int p = blockIdx.x * 256 + threadIdx.x;
    if (p < P) {
        const size_t i = (size_t)k * P + p;
        const int b = pout[i] * K_TAPS + k;
        const int pos = atomicAdd(&S[b + 1], 1);
        E[pos] = pin[i];
    }
}

// ---------------------------------------------------------------------------
// W pre-transpose: W[k][c][d] -> Wt[k][d][c] (lane d's slice contiguous)
// ---------------------------------------------------------------------------
__global__ __launch_bounds__(256)
void transpose_w_kernel(const float* __restrict__ W, float* __restrict__ Wt, int C)
{
    const int k = blockIdx.x;
    const float* __restrict__ Wk  = W  + (size_t)k * C * DCH;
    float* __restrict__       Wtk = Wt + (size_t)k * C * DCH;
    for (int i = threadIdx.x; i < C * DCH; i += 256) {
        const int c = i >> 6;
        const int d = i & 63;
        Wtk[(size_t)d * C + c] = Wk[i];
    }
}

// ---------------------------------------------------------------------------
// Output-stationary gather conv v6.
//  - W pairs loaded per k by VOLATILE inline-asm global_load_dwordx2 into
//    "=v" f32x2 values: un-rematerializable -> guaranteed VGPR-resident
//    across the whole entry loop (rounds 5-7 showed compiler-load pins fail).
//  - Explicit s_waitcnt vmcnt(0) asm re-defining the W values (dep-chain
//    ordering, rule-18 pattern) before use.
//  - v_pk_fma_f32 inner loop: 2 FLOPs/lane/cy (fp32 peak path).
//  - Feats as compiler f32x4 broadcast loads (round-4 proven path).
//  - Fused BN partial-stats epilogue; each output row written exactly once.
// ---------------------------------------------------------------------------
template <int C, int RW, int MINW>
__global__ __launch_bounds__(256, MINW)
void gather_conv_kernel(const float* __restrict__ x,
                        const float* __restrict__ Wt,
                        const int* __restrict__ S,
                        const int* __restrict__ E,
                        float* __restrict__ y,
                        float* __restrict__ stats,
                        int n_out)
{
    const int lane = threadIdx.x & 63;
    const int wave = threadIdx.x >> 6;
    const int r0 = blockIdx.x * (4 * RW) + wave * RW;
    constexpr int SN = K_TAPS * RW + 1;

    __shared__ int sS[4][SN];
    __shared__ float red[2][4][64];
    {
        const int base = r0 * K_TAPS;
        const int NBtot = n_out * K_TAPS;
        for (int i = lane; i < SN; i += 64) {
            int v = 0;
            if (r0 < n_out) {
                int gi = base + i;
                if (gi > NBtot) gi = NBtot;
                v = S[gi];
            }
            sS[wave][i] = v;
        }
    }
    __syncthreads();

    f32x2 accA[RW], accB[RW];
#pragma unroll
    for (int i = 0; i < RW; ++i) { accA[i] = (f32x2)0.f; accB[i] = (f32x2)0.f; }

    for (int k = 0; k < K_TAPS; ++k) {
        // ---- volatile-asm W loads: lane's contiguous slice as c-pairs ----
        const float* wbase = Wt + ((size_t)k * DCH + lane) * C;
        f32x2 w2[C / 2];
#pragma unroll
        for (int j = 0; j < C / 2; ++j) {
            const float* wp = wbase + 2 * j;
            asm volatile("global_load_dwordx2 %0, %1, off" : "=v"(w2[j]) : "v"(wp));
        }
        // drain our loads; re-define values so every use is ordered after wait
        asm volatile("s_waitcnt vmcnt(0)"
                     : "+v"(w2[0]), "+v"(w2[1]), "+v"(w2[2]), "+v"(w2[3]),
                       "+v"(w2[4]), "+v"(w2[5]), "+v"(w2[6]), "+v"(w2[7])
                     :: "memory");
        asm volatile(""
                     : "+v"(w2[8]), "+v"(w2[9]), "+v"(w2[10]), "+v"(w2[11]),
                       "+v"(w2[12]), "+v"(w2[13]), "+v"(w2[14]), "+v"(w2[15]));
        if constexpr (C == 64) {
            asm volatile(""
                         : "+v"(w2[16]), "+v"(w2[17]), "+v"(w2[18]), "+v"(w2[19]),
                           "+v"(w2[20]), "+v"(w2[21]), "+v"(w2[22]), "+v"(w2[23]));
            asm volatile(""
                         : "+v"(w2[24]), "+v"(w2[25]), "+v"(w2[26]), "+v"(w2[27]),
                           "+v"(w2[28]), "+v"(w2[29]), "+v"(w2[30]), "+v"(w2[31]));
        }

#pragma unroll
        for (int ri = 0; ri < RW; ++ri) {
            const int e0 = sS[wave][ri * K_TAPS + k];
            const int e1 = sS[wave][ri * K_TAPS + k + 1];
            f32x2 aA = accA[ri], aB = accB[ri];
            for (int e = e0; e < e1; ++e) {
                const int irow = E[e];
                const f32x4* __restrict__ fr =
                    reinterpret_cast<const f32x4*>(x + (size_t)irow * C);
#pragma unroll
                for (int j = 0; j < C / 4; ++j) {
                    const f32x4 fv = fr[j];
                    PKFMA(aA, fv.lo, w2[2 * j]);
                    PKFMA(aB, fv.hi, w2[2 * j + 1]);
                }
            }
            accA[ri] = aA; accB[ri] = aB;
        }
    }

    // epilogue: write rows + per-block BN partial stats
    float s = 0.f, ss = 0.f;
#pragma unroll
    for (int ri = 0; ri < RW; ++ri) {
        const int r = r0 + ri;
        if (r < n_out) {
            const float v = accA[ri].x + accA[ri].y + accB[ri].x + accB[ri].y;
            y[(size_t)r * DCH + lane] = v;
            s += v;
            ss += v * v;
        }
    }
    red[0][wave][lane] = s;
    red[1][wave][lane] = ss;
    __syncthreads();
    if (threadIdx.x < 64) {
        const float t = red[0][0][lane] + red[0][1][lane] + red[0][2][lane] + red[0][3][lane];
        unsafeAtomicAdd(&stats[lane], t);
    } else if (threadIdx.x < 128) {
        const float t = red[1][0][lane] + red[1][1][lane] + red[1][2][lane] + red[1][3][lane];
        unsafeAtomicAdd(&stats[64 + lane], t);
    }
}

__global__ __launch_bounds__(256)
void bn_apply_kernel(float* __restrict__ x, int n_elem,
                     const float* __restrict__ stats,
                     const float* __restrict__ g,
                     const float* __restrict__ b,
                     float inv_n)
{
    const int d = threadIdx.x & 63;
    const float m   = stats[d] * inv_n;
    const float var = stats[64 + d] * inv_n - m * m;
    const float sc  = g[d] * rsqrtf(var + BN_EPS);
    const float sh  = b[d] - m * sc;
    for (int i = blockIdx.x * 256 + threadIdx.x; i < n_elem; i += gridDim.x * 256) {
        float v = x[i];
        x[i] = fmaxf(__builtin_fmaf(v, sc, sh), 0.f);
    }
}

__global__ __launch_bounds__(256)
void bn_final_kernel(float* __restrict__ y2, const float* __restrict__ xnet,
                     int n_elem,
                     const float* __restrict__ stats,
                     const float* __restrict__ g,
                     const float* __restrict__ b,
                     float inv_n)
{
    const int d = threadIdx.x & 63;
    const float m   = stats[d] * inv_n;
    const float var = stats[64 + d] * inv_n - m * m;
    const float sc  = g[d] * rsqrtf(var + BN_EPS);
    const float sh  = b[d] - m * sc;
    for (int i = blockIdx.x * 256 + threadIdx.x; i < n_elem; i += gridDim.x * 256) {
        float v = y2[i];
        y2[i] = xnet[i] + fmaxf(__builtin_fmaf(v, sc, sh), 0.f);
    }
}

extern "C" void kernel_launch(void* const* d_in, const int* in_sizes, int n_in,
                              void* d_out, int out_size, void* d_ws, size_t ws_size,
                              hipStream_t stream)
{
    const float* feats  = (const float*)d_in[0];
    const float* W_down = (const float*)d_in[1];
    const float* g0     = (const float*)d_in[2];
    const float* b0     = (const float*)d_in[3];
    const float* W1     = (const float*)d_in[4];
    const float* g1     = (const float*)d_in[5];
    const float* b1     = (const float*)d_in[6];
    const float* W2     = (const float*)d_in[7];
    const float* g2     = (const float*)d_in[8];
    const float* b2     = (const float*)d_in[9];
    const int* pdi      = (const int*)d_in[10];
    const int* pdo      = (const int*)d_in[11];
    const int* psi      = (const int*)d_in[12];
    const int* pso      = (const int*)d_in[13];

    const int P1     = in_sizes[10] / K_TAPS;
    const int P2     = in_sizes[12] / K_TAPS;
    const int M1     = in_sizes[10];
    const int n_out  = out_size / DCH;
    const int n_elem = n_out * DCH;
    const int NB     = n_out * K_TAPS;
    const float inv_n = 1.0f / (float)n_out;

    float* out = (float*)d_out;

    // ---- workspace layout (~30.5 MB) ----
    float* xnet  = (float*)d_ws;
    int*   counts = (int*)d_ws;          // overlays xnet during CSR builds
    float* stats = xnet + (size_t)n_elem;
    int* S = (int*)(stats + 384);
    int* E = S + (NB + 1);
    int* partials = E + M1;              // M1 >= M2
    float* Wt_dn = (float*)(partials + 1024);   // 27*64*32
    float* Wt_s1 = Wt_dn + 27 * 32 * DCH;       // 27*64*64
    float* Wt_s2 = Wt_s1 + 27 * DCH * DCH;      // 27*64*64

    float* st0 = stats;
    float* st1 = stats + 128;
    float* st2 = stats + 256;

    const dim3 blk(256);
    const dim3 gridH1((P1 + 255) / 256, K_TAPS);
    const dim3 gridH2((P2 + 255) / 256, K_TAPS);
    const int nchunks = (NB + SCAN_CHUNK - 1) / SCAN_CHUNK;
    const int ewBlocks = 2048;

    // down: C=32, RW=4 (16 rows/block) -> 3125 blocks
    constexpr int RW_DN = 4;
    const int gatherBlocksDn = (n_out + 4 * RW_DN - 1) / (4 * RW_DN);
    // subm: C=64, RW=8 (32 rows/block) -> 1563 blocks
    constexpr int RW_SM = 8;
    const int gatherBlocksSm = (n_out + 4 * RW_SM - 1) / (4 * RW_SM);

    hipMemsetAsync(stats, 0, sizeof(float) * 384, stream);

    // ---- W transposes ----
    transpose_w_kernel<<<K_TAPS, blk, 0, stream>>>(W_down, Wt_dn, 32);
    transpose_w_kernel<<<K_TAPS, blk, 0, stream>>>(W1, Wt_s1, 64);
    transpose_w_kernel<<<K_TAPS, blk, 0, stream>>>(W2, Wt_s2, 64);

    // ---- build down CSR ----
    hipMemsetAsync(counts, 0, sizeof(int) * (size_t)NB, stream);
    hist_kernel<<<gridH1, blk, 0, stream>>>(pdo, P1, counts);
    scan_sum_kernel<<<nchunks, blk, 0, stream>>>(counts, NB, partials);
    scan_partials_kernel<<<1, 512, 0, stream>>>(partials, nchunks);
    scan_write_kernel<<<nchunks, blk, 0, stream>>>(counts, NB, partials, S);
    fill_kernel<<<gridH1, blk, 0, stream>>>(pdi, pdo, P1, S, E);

    // ---- DownBlock: y0 = conv(feats) -> d_out (+stats) ; bnrelu in place ----
    gather_conv_kernel<32, RW_DN, 3><<<gatherBlocksDn, blk, 0, stream>>>(feats, Wt_dn, S, E, out, st0, n_out);
    bn_apply_kernel<<<ewBlocks, blk, 0, stream>>>(out, n_elem, st0, g0, b0, inv_n);

    // ---- rebuild CSR region as subm CSR (down CSR now dead) ----
    hipMemsetAsync(counts, 0, sizeof(int) * (size_t)NB, stream);
    hist_kernel<<<gridH2, blk, 0, stream>>>(pso, P2, counts);
    scan_sum_kernel<<<nchunks, blk, 0, stream>>>(counts, NB, partials);
    scan_partials_kernel<<<1, 512, 0, stream>>>(partials, nchunks);
    scan_write_kernel<<<nchunks, blk, 0, stream>>>(counts, NB, partials, S);
    fill_kernel<<<gridH2, blk, 0, stream>>>(psi, pso, P2, S, E);

    // ---- ResBlock conv1: y1 = conv(x0) -> xnet (+stats) ; bnrelu in place ----
    gather_conv_kernel<64, RW_SM, 2><<<gatherBlocksSm, blk, 0, stream>>>(out, Wt_s1, S, E, xnet, st1, n_out);
    bn_apply_kernel<<<ewBlocks, blk, 0, stream>>>(xnet, n_elem, st1, g1, b1, inv_n);

    // ---- ResBlock conv2: y2 = conv(x_net) -> d_out (+stats) ----
    gather_conv_kernel<64, RW_SM, 2><<<gatherBlocksSm, blk, 0, stream>>>(xnet, Wt_s2, S, E, out, st2, n_out);

    // ---- out = x_net + relu(bn(y2)) ----
    bn_final_kernel<<<ewBlocks, blk, 0, stream>>>(out, xnet, n_elem, st2, g2, b2, inv_n);
}

// Round 9
// 3067.534 us; speedup vs baseline: 1.6218x; 1.6218x over previous
//
#include <hip/hip_runtime.h>
#include <hip/hip_bf16.h>

#define K_TAPS 27
#define DCH 64
#define BN_EPS 1e-5f
#define SCAN_CHUNK 4096

typedef float f32x4 __attribute__((ext_vector_type(4)));
typedef float f32x2 __attribute__((ext_vector_type(2)));

// ---------------------------------------------------------------------------
// CSR build: histogram over buckets b = orow*27 + k
// ---------------------------------------------------------------------------
__global__ __launch_bounds__(256)
void hist_kernel(const int* __restrict__ pout, int P, int* __restrict__ counts)
{
    const int k = blockIdx.y;
    const int p = blockIdx.x * 256 + threadIdx.x;
    if (p < P) {
        const int r = pout[(size_t)k * P + p];
        atomicAdd(&counts[r * K_TAPS + k], 1);
    }
}

__global__ __launch_bounds__(256)
void scan_sum_kernel(const int* __restrict__ counts, int n, int* __restrict__ partials)
{
    __shared__ int sm[256];
    const int base = blockIdx.x * SCAN_CHUNK;
    int s = 0;
#pragma unroll
    for (int j = 0; j < 16; ++j) {
        const int i = base + j * 256 + threadIdx.x;
        if (i < n) s += counts[i];
    }
    sm[threadIdx.x] = s;
    __syncthreads();
    for (int off = 128; off > 0; off >>= 1) {
        if (threadIdx.x < off) sm[threadIdx.x] += sm[threadIdx.x + off];
        __syncthreads();
    }
    if (threadIdx.x == 0) partials[blockIdx.x] = sm[0];
}

__global__ __launch_bounds__(512)
void scan_partials_kernel(int* __restrict__ partials, int n)
{
    __shared__ int sm[512];
    const int t = threadIdx.x;
    const int v = (t < n) ? partials[t] : 0;
    sm[t] = v;
    __syncthreads();
    for (int off = 1; off < 512; off <<= 1) {
        int tv = 0;
        if (t >= off) tv = sm[t - off];
        __syncthreads();
        if (t >= off) sm[t] += tv;
        __syncthreads();
    }
    if (t < n) partials[t] = sm[t] - v;  // exclusive
}

__global__ __launch_bounds__(256)
void scan_write_kernel(const int* __restrict__ counts, int n,
                       const int* __restrict__ chunkoff, int* __restrict__ S)
{
    __shared__ int sm[256];
    const int base = blockIdx.x * SCAN_CHUNK + threadIdx.x * 16;
    int v[16];
    int s = 0;
#pragma unroll
    for (int j = 0; j < 16; ++j) {
        const int i = base + j;
        v[j] = (i < n) ? counts[i] : 0;
        s += v[j];
    }
    sm[threadIdx.x] = s;
    __syncthreads();
    for (int off = 1; off < 256; off <<= 1) {
        int tv = 0;
        if (threadIdx.x >= off) tv = sm[threadIdx.x - off];
        __syncthreads();
        if (threadIdx.x >= off) sm[threadIdx.x] += tv;
        __syncthreads();
    }
    int run = chunkoff[blockIdx.x] + sm[threadIdx.x] - s;  // exclusive base
#pragma unroll
    for (int j = 0; j < 16; ++j) {
        const int i = base + j;
        if (i < n) S[i + 1] = run;
        run += v[j];
    }
    if (blockIdx.x == 0 && threadIdx.x == 0) S[0] = 0;
}

__global__ __launch_bounds__(256)
void fill_kernel(const int* __restrict__ pin, const int* __restrict__ pout, int P,
                 int* __restrict__ S, int* __restrict__ E)
{
    const int k = blockIdx.y;
    const int p = blockIdx.x * 256 + threadIdx.x;
    if (p < P) {
        const size_t i = (size_t)k * P + p;
        const int b = pout[i] * K_TAPS + k;
        const int pos = atomicAdd(&S[b + 1], 1);
        E[pos] = pin[i];
    }
}

// ---------------------------------------------------------------------------
// Merged W pre-transpose: W[k][c][d] -> Wt[k][d][c] for all three weights.
// blocks 0..26 = W_down (C=32), 27..53 = W1, 54..80 = W2.
// ---------------------------------------------------------------------------
__global__ __launch_bounds__(256)
void transpose_w_kernel(const float* __restrict__ Wd,
                        const float* __restrict__ W1,
                        const float* __restrict__ W2,
                        float* __restrict__ Wt_d,
                        float* __restrict__ Wt_1,
                        float* __restrict__ Wt_2)
{
    int b = blockIdx.x;
    const float* W;
    float* Wt;
    int C, k;
    if (b < 27)      { W = Wd; Wt = Wt_d; C = 32; k = b; }
    else if (b < 54) { W = W1; Wt = Wt_1; C = 64; k = b - 27; }
    else             { W = W2; Wt = Wt_2; C = 64; k = b - 54; }
    const float* Wk  = W  + (size_t)k * C * DCH;
    float*       Wtk = Wt + (size_t)k * C * DCH;
    for (int i = threadIdx.x; i < C * DCH; i += 256) {
        const int c = i >> 6;
        const int d = i & 63;
        Wtk[(size_t)d * C + c] = Wk[i];
    }
}

// ---------------------------------------------------------------------------
// Output-stationary gather conv v7 (r4 structure + residency fix + pk_fma).
//  - Wt passed as PLAIN float* (no const/restrict): W loads are NOT invariant
//    -> register allocator cannot rematerialize them into the e-loop (the
//    r4-r7 failure mechanism) -> per-k W slice stays VGPR-resident.
//  - asm memory fence after W loads blocks any residual load sinking.
//  - Transposed W: lane's slice contiguous -> C/2 dwordx2 loads per k.
//  - f32x2 arithmetic -> v_pk_fma_f32 (2 FLOP/lane/cy), halves FMA issue.
//  - LDS-staged S slices, fused BN partial-stats epilogue (r5-proven).
// ---------------------------------------------------------------------------
template <int C, int RW, int MINW>
__global__ __launch_bounds__(256, MINW)
void gather_conv_kernel(const float* __restrict__ x,
                        float* Wt,                    // intentionally no const/restrict
                        const int* __restrict__ S,
                        const int* __restrict__ E,
                        float* __restrict__ y,
                        float* __restrict__ stats,
                        int n_out)
{
    const int lane = threadIdx.x & 63;
    const int wave = threadIdx.x >> 6;
    const int r0 = blockIdx.x * (4 * RW) + wave * RW;
    constexpr int SN = K_TAPS * RW + 1;

    __shared__ int sS[4][SN];
    __shared__ float red[2][4][64];
    {
        const int base = r0 * K_TAPS;
        const int NBtot = n_out * K_TAPS;
        for (int i = lane; i < SN; i += 64) {
            int v = 0;
            if (r0 < n_out) {
                int gi = base + i;
                if (gi > NBtot) gi = NBtot;
                v = S[gi];
            }
            sS[wave][i] = v;
        }
    }
    __syncthreads();

    f32x2 accA[RW], accB[RW];
#pragma unroll
    for (int i = 0; i < RW; ++i) { accA[i] = (f32x2)0.f; accB[i] = (f32x2)0.f; }

    for (int k = 0; k < K_TAPS; ++k) {
        // per-k weight slice for this lane's output channel: contiguous pairs
        f32x2 w[C / 2];
        const float* wp = Wt + ((size_t)k * DCH + lane) * C;
#pragma unroll
        for (int j = 0; j < C / 2; ++j)
            w[j] = *reinterpret_cast<const f32x2*>(wp + 2 * j);
        asm volatile("" ::: "memory");  // fence: no sinking past this point

#pragma unroll
        for (int ri = 0; ri < RW; ++ri) {
            const int e0 = sS[wave][ri * K_TAPS + k];
            const int e1 = sS[wave][ri * K_TAPS + k + 1];
            f32x2 aA = accA[ri], aB = accB[ri];
            for (int e = e0; e < e1; ++e) {
                const int irow = E[e];
                const f32x4* __restrict__ fr =
                    reinterpret_cast<const f32x4*>(x + (size_t)irow * C);
#pragma unroll
                for (int j = 0; j < C / 4; ++j) {
                    const f32x4 fv = fr[j];
                    const f32x2 flo = __builtin_shufflevector(fv, fv, 0, 1);
                    const f32x2 fhi = __builtin_shufflevector(fv, fv, 2, 3);
                    aA += flo * w[2 * j];      // v_pk_fma_f32 (fp-contract)
                    aB += fhi * w[2 * j + 1];
                }
            }
            accA[ri] = aA; accB[ri] = aB;
        }
    }

    // epilogue: write rows + per-block BN partial stats
    float s = 0.f, ss = 0.f;
#pragma unroll
    for (int ri = 0; ri < RW; ++ri) {
        const int r = r0 + ri;
        if (r < n_out) {
            const float v = accA[ri].x + accA[ri].y + accB[ri].x + accB[ri].y;
            y[(size_t)r * DCH + lane] = v;
            s += v;
            ss += v * v;
        }
    }
    red[0][wave][lane] = s;
    red[1][wave][lane] = ss;
    __syncthreads();
    if (threadIdx.x < 64) {
        const float t = red[0][0][lane] + red[0][1][lane] + red[0][2][lane] + red[0][3][lane];
        unsafeAtomicAdd(&stats[lane], t);
    } else if (threadIdx.x < 128) {
        const float t = red[1][0][lane] + red[1][1][lane] + red[1][2][lane] + red[1][3][lane];
        unsafeAtomicAdd(&stats[64 + lane], t);
    }
}

__global__ __launch_bounds__(256)
void bn_apply_kernel(float* __restrict__ x, int n_elem,
                     const float* __restrict__ stats,
                     const float* __restrict__ g,
                     const float* __restrict__ b,
                     float inv_n)
{
    const int d = threadIdx.x & 63;
    const float m   = stats[d] * inv_n;
    const float var = stats[64 + d] * inv_n - m * m;
    const float sc  = g[d] * rsqrtf(var + BN_EPS);
    const float sh  = b[d] - m * sc;
    for (int i = blockIdx.x * 256 + threadIdx.x; i < n_elem; i += gridDim.x * 256) {
        float v = x[i];
        x[i] = fmaxf(__builtin_fmaf(v, sc, sh), 0.f);
    }
}

__global__ __launch_bounds__(256)
void bn_final_kernel(float* __restrict__ y2, const float* __restrict__ xnet,
                     int n_elem,
                     const float* __restrict__ stats,
                     const float* __restrict__ g,
                     const float* __restrict__ b,
                     float inv_n)
{
    const int d = threadIdx.x & 63;
    const float m   = stats[d] * inv_n;
    const float var = stats[64 + d] * inv_n - m * m;
    const float sc  = g[d] * rsqrtf(var + BN_EPS);
    const float sh  = b[d] - m * sc;
    for (int i = blockIdx.x * 256 + threadIdx.x; i < n_elem; i += gridDim.x * 256) {
        float v = y2[i];
        y2[i] = xnet[i] + fmaxf(__builtin_fmaf(v, sc, sh), 0.f);
    }
}

extern "C" void kernel_launch(void* const* d_in, const int* in_sizes, int n_in,
                              void* d_out, int out_size, void* d_ws, size_t ws_size,
                              hipStream_t stream)
{
    const float* feats  = (const float*)d_in[0];
    const float* W_down = (const float*)d_in[1];
    const float* g0     = (const float*)d_in[2];
    const float* b0     = (const float*)d_in[3];
    const float* W1     = (const float*)d_in[4];
    const float* g1     = (const float*)d_in[5];
    const float* b1     = (const float*)d_in[6];
    const float* W2     = (const float*)d_in[7];
    const float* g2     = (const float*)d_in[8];
    const float* b2     = (const float*)d_in[9];
    const int* pdi      = (const int*)d_in[10];
    const int* pdo      = (const int*)d_in[11];
    const int* psi      = (const int*)d_in[12];
    const int* pso      = (const int*)d_in[13];

    const int P1     = in_sizes[10] / K_TAPS;
    const int P2     = in_sizes[12] / K_TAPS;
    const int M1     = in_sizes[10];
    const int n_out  = out_size / DCH;
    const int n_elem = n_out * DCH;
    const int NB     = n_out * K_TAPS;
    const float inv_n = 1.0f / (float)n_out;

    float* out = (float*)d_out;

    // ---- workspace layout (~30.5 MB, r6/r7-proven watermark) ----
    float* xnet  = (float*)d_ws;
    int*   counts = (int*)d_ws;          // overlays xnet during CSR builds
    float* stats = xnet + (size_t)n_elem;
    int* S = (int*)(stats + 384);
    int* E = S + (NB + 1);
    int* partials = E + M1;              // M1 >= M2
    float* Wt_dn = (float*)(partials + 1024);   // 27*64*32
    float* Wt_s1 = Wt_dn + 27 * 32 * DCH;       // 27*64*64
    float* Wt_s2 = Wt_s1 + 27 * DCH * DCH;      // 27*64*64

    float* st0 = stats;
    float* st1 = stats + 128;
    float* st2 = stats + 256;

    const dim3 blk(256);
    const dim3 gridH1((P1 + 255) / 256, K_TAPS);
    const dim3 gridH2((P2 + 255) / 256, K_TAPS);
    const int nchunks = (NB + SCAN_CHUNK - 1) / SCAN_CHUNK;
    const int ewBlocks = 2048;

    // down: C=32, RW=4 (16 rows/block) -> 3125 blocks, MINW=4 (budget 128)
    constexpr int RW_DN = 4;
    const int gatherBlocksDn = (n_out + 4 * RW_DN - 1) / (4 * RW_DN);
    // subm: C=64, RW=8 (32 rows/block) -> 1563 blocks, MINW=2 (budget 256)
    constexpr int RW_SM = 8;
    const int gatherBlocksSm = (n_out + 4 * RW_SM - 1) / (4 * RW_SM);

    hipMemsetAsync(stats, 0, sizeof(float) * 384, stream);

    // ---- merged W transposes ----
    transpose_w_kernel<<<81, blk, 0, stream>>>(W_down, W1, W2, Wt_dn, Wt_s1, Wt_s2);

    // ---- build down CSR ----
    hipMemsetAsync(counts, 0, sizeof(int) * (size_t)NB, stream);
    hist_kernel<<<gridH1, blk, 0, stream>>>(pdo, P1, counts);
    scan_sum_kernel<<<nchunks, blk, 0, stream>>>(counts, NB, partials);
    scan_partials_kernel<<<1, 512, 0, stream>>>(partials, nchunks);
    scan_write_kernel<<<nchunks, blk, 0, stream>>>(counts, NB, partials, S);
    fill_kernel<<<gridH1, blk, 0, stream>>>(pdi, pdo, P1, S, E);

    // ---- DownBlock: y0 = conv(feats) -> d_out (+stats) ; bnrelu in place ----
    gather_conv_kernel<32, RW_DN, 4><<<gatherBlocksDn, blk, 0, stream>>>(feats, Wt_dn, S, E, out, st0, n_out);
    bn_apply_kernel<<<ewBlocks, blk, 0, stream>>>(out, n_elem, st0, g0, b0, inv_n);

    // ---- rebuild CSR region as subm CSR (down CSR now dead) ----
    hipMemsetAsync(counts, 0, sizeof(int) * (size_t)NB, stream);
    hist_kernel<<<gridH2, blk, 0, stream>>>(pso, P2, counts);
    scan_sum_kernel<<<nchunks, blk, 0, stream>>>(counts, NB, partials);
    scan_partials_kernel<<<1, 512, 0, stream>>>(partials, nchunks);
    scan_write_kernel<<<nchunks, blk, 0, stream>>>(counts, NB, partials, S);
    fill_kernel<<<gridH2, blk, 0, stream>>>(psi, pso, P2, S, E);

    // ---- ResBlock conv1: y1 = conv(x0) -> xnet (+stats) ; bnrelu in place ----
    gather_conv_kernel<64, RW_SM, 2><<<gatherBlocksSm, blk, 0, stream>>>(out, Wt_s1, S, E, xnet, st1, n_out);
    bn_apply_kernel<<<ewBlocks, blk, 0, stream>>>(xnet, n_elem, st1, g1, b1, inv_n);

    // ---- ResBlock conv2: y2 = conv(x_net) -> d_out (+stats) ----
    gather_conv_kernel<64, RW_SM, 2><<<gatherBlocksSm, blk, 0, stream>>>(xnet, Wt_s2, S, E, out, st2, n_out);

    // ---- out = x_net + relu(bn(y2)) ----
    bn_final_kernel<<<ewBlocks, blk, 0, stream>>>(out, xnet, n_elem, st2, g2, b2, inv_n);
}

// Round 10
// 3040.785 us; speedup vs baseline: 1.6361x; 1.0088x over previous
//
#include <hip/hip_runtime.h>
#include <hip/hip_bf16.h>

#define K_TAPS 27
#define DCH 64
#define BN_EPS 1e-5f
#define SCAN_CHUNK 4096

typedef float f32x4 __attribute__((ext_vector_type(4)));

// ---------------------------------------------------------------------------
// CSR build: histogram over buckets b = orow*27 + k
// ---------------------------------------------------------------------------
__global__ __launch_bounds__(256)
void hist_kernel(const int* __restrict__ pout, int P, int* __restrict__ counts)
{
    const int k = blockIdx.y;
    const int p = blockIdx.x * 256 + threadIdx.x;
    if (p < P) {
        const int r = pout[(size_t)k * P + p];
        atomicAdd(&counts[r * K_TAPS + k], 1);
    }
}

__global__ __launch_bounds__(256)
void scan_sum_kernel(const int* __restrict__ counts, int n, int* __restrict__ partials)
{
    __shared__ int sm[256];
    const int base = blockIdx.x * SCAN_CHUNK;
    int s = 0;
#pragma unroll
    for (int j = 0; j < 16; ++j) {
        const int i = base + j * 256 + threadIdx.x;
        if (i < n) s += counts[i];
    }
    sm[threadIdx.x] = s;
    __syncthreads();
    for (int off = 128; off > 0; off >>= 1) {
        if (threadIdx.x < off) sm[threadIdx.x] += sm[threadIdx.x + off];
        __syncthreads();
    }
    if (threadIdx.x == 0) partials[blockIdx.x] = sm[0];
}

__global__ __launch_bounds__(512)
void scan_partials_kernel(int* __restrict__ partials, int n)
{
    __shared__ int sm[512];
    const int t = threadIdx.x;
    const int v = (t < n) ? partials[t] : 0;
    sm[t] = v;
    __syncthreads();
    for (int off = 1; off < 512; off <<= 1) {
        int tv = 0;
        if (t >= off) tv = sm[t - off];
        __syncthreads();
        if (t >= off) sm[t] += tv;
        __syncthreads();
    }
    if (t < n) partials[t] = sm[t] - v;  // exclusive
}

__global__ __launch_bounds__(256)
void scan_write_kernel(const int* __restrict__ counts, int n,
                       const int* __restrict__ chunkoff, int* __restrict__ S)
{
    __shared__ int sm[256];
    const int base = blockIdx.x * SCAN_CHUNK + threadIdx.x * 16;
    int v[16];
    int s = 0;
#pragma unroll
    for (int j = 0; j < 16; ++j) {
        const int i = base + j;
        v[j] = (i < n) ? counts[i] : 0;
        s += v[j];
    }
    sm[threadIdx.x] = s;
    __syncthreads();
    for (int off = 1; off < 256; off <<= 1) {
        int tv = 0;
        if (threadIdx.x >= off) tv = sm[threadIdx.x - off];
        __syncthreads();
        if (threadIdx.x >= off) sm[threadIdx.x] += tv;
        __syncthreads();
    }
    int run = chunkoff[blockIdx.x] + sm[threadIdx.x] - s;  // exclusive base
#pragma unroll
    for (int j = 0; j < 16; ++j) {
        const int i = base + j;
        if (i < n) S[i + 1] = run;
        run += v[j];
    }
    if (blockIdx.x == 0 && threadIdx.x == 0) S[0] = 0;
}

__global__ __launch_bounds__(256)
void fill_kernel(const int* __restrict__ pin, const int* __restrict__ pout, int P,
                 int* __restrict__ S, int* __restrict__ E)
{
    const int k = blockIdx.y;
    const int p = blockIdx.x * 256 + threadIdx.x;
    if (p < P) {
        const size_t i = (size_t)k * P + p;
        const int b = pout[i] * K_TAPS + k;
        const int pos = atomicAdd(&S[b + 1], 1);
        E[pos] = pin[i];
    }
}

// ---------------------------------------------------------------------------
// Merged W pre-transpose: W[k][c][d] -> Wt[k][d][c].
// blocks 0..26 = W_down (C=32), 27..53 = W1, 54..80 = W2.
// ---------------------------------------------------------------------------
__global__ __launch_bounds__(256)
void transpose_w_kernel(const float* __restrict__ Wd,
                        const float* __restrict__ W1,
                        const float* __restrict__ W2,
                        float* __restrict__ Wt_d,
                        float* __restrict__ Wt_1,
                        float* __restrict__ Wt_2)
{
    int b = blockIdx.x;
    const float* W;
    float* Wt;
    int C, k;
    if (b < 27)      { W = Wd; Wt = Wt_d; C = 32; k = b; }
    else if (b < 54) { W = W1; Wt = Wt_1; C = 64; k = b - 27; }
    else             { W = W2; Wt = Wt_2; C = 64; k = b - 54; }
    const float* Wk  = W  + (size_t)k * C * DCH;
    float*       Wtk = Wt + (size_t)k * C * DCH;
    for (int i = threadIdx.x; i < C * DCH; i += 256) {
        const int c = i >> 6;
        const int d = i & 63;
        Wtk[(size_t)d * C + c] = Wk[i];
    }
}

// ---------------------------------------------------------------------------
// Output-stationary gather conv v8: LDS-staged weights.
//  - W[k] staged per block per k into LDS (double-buffered), XOR-swizzled
//    16B slots: lane-stride-C ds_read_b128 runs at the LDS BW floor (no
//    serializing conflicts). No register-residency dependence at all --
//    the r4-r9 allocator fight is over; ds_read remat is cheap by design.
//  - e-loop pair-unrolled: 2 entries of a bucket share each W read (halves
//    LDS traffic where buckets >= 2, i.e. the down conv).
//  - Feats: r4-proven per-lane float4 broadcast loads + scalar fmac chains.
//  - Fused BN partial-stats epilogue; each output row written exactly once.
// ---------------------------------------------------------------------------
template <int C, int RW, int MINW>
__global__ __launch_bounds__(256, MINW)
void gather_conv_kernel(const float* __restrict__ x,
                        const float* __restrict__ Wt,
                        const int* __restrict__ S,
                        const int* __restrict__ E,
                        float* __restrict__ y,
                        float* __restrict__ stats,
                        int n_out)
{
    const int tid  = threadIdx.x;
    const int lane = tid & 63;
    const int wave = tid >> 6;
    const int r0 = blockIdx.x * (4 * RW) + wave * RW;
    constexpr int SN  = K_TAPS * RW + 1;
    constexpr int WSZ = 64 * C;      // floats per k-slice
    constexpr int NJ  = C / 4;       // 16B groups per lane row

    __shared__ float sW[2][WSZ];
    __shared__ int   sS[4][SN];
    __shared__ float red[2][4][64];

    // stage this wave's S slice
    {
        const int base = r0 * K_TAPS;
        const int NBtot = n_out * K_TAPS;
        for (int i = lane; i < SN; i += 64) {
            int v = 0;
            if (r0 < n_out) {
                int gi = base + i;
                if (gi > NBtot) gi = NBtot;
                v = S[gi];
            }
            sS[wave][i] = v;
        }
    }

    // cooperative W[k] stage: global (coalesced f32x4) -> swizzled LDS
    auto stage = [&](int k, int buf) {
#pragma unroll
        for (int t = 0; t < WSZ / 4 / 256; ++t) {
            const int i = t * 256 + tid;        // [0, WSZ/4)
            const int d = i / NJ;
            const int j = i % NJ;
            const f32x4 v = *reinterpret_cast<const f32x4*>(
                Wt + (size_t)k * WSZ + (size_t)d * C + j * 4);
            *reinterpret_cast<f32x4*>(&sW[buf][d * C + ((j ^ (d & 7)) << 2)]) = v;
        }
    };
    stage(0, 0);
    __syncthreads();

    float acc0[RW], acc1[RW], acc2[RW], acc3[RW];
#pragma unroll
    for (int i = 0; i < RW; ++i) { acc0[i] = 0.f; acc1[i] = 0.f; acc2[i] = 0.f; acc3[i] = 0.f; }

    const int wbase = lane * C;

    for (int k = 0; k < K_TAPS; ++k) {
        if (k + 1 < K_TAPS) stage(k + 1, (k + 1) & 1);
        const int buf = k & 1;

#pragma unroll
        for (int ri = 0; ri < RW; ++ri) {
            const int e0 = sS[wave][ri * K_TAPS + k];
            const int e1 = sS[wave][ri * K_TAPS + k + 1];
            float a0 = acc0[ri], a1 = acc1[ri], a2 = acc2[ri], a3 = acc3[ri];
            int e = e0;
            for (; e + 1 < e1; e += 2) {           // paired: share W reads
                const int i0 = E[e];
                const int i1 = E[e + 1];
                const float4* __restrict__ fr0 =
                    reinterpret_cast<const float4*>(x + (size_t)i0 * C);
                const float4* __restrict__ fr1 =
                    reinterpret_cast<const float4*>(x + (size_t)i1 * C);
#pragma unroll
                for (int j = 0; j < NJ; ++j) {
                    const f32x4 wv = *reinterpret_cast<const f32x4*>(
                        &sW[buf][wbase + ((j ^ (lane & 7)) << 2)]);
                    const float4 f0 = fr0[j];
                    const float4 f1 = fr1[j];
                    a0 = __builtin_fmaf(f0.x, wv.x, a0);
                    a1 = __builtin_fmaf(f0.y, wv.y, a1);
                    a0 = __builtin_fmaf(f0.z, wv.z, a0);
                    a1 = __builtin_fmaf(f0.w, wv.w, a1);
                    a2 = __builtin_fmaf(f1.x, wv.x, a2);
                    a3 = __builtin_fmaf(f1.y, wv.y, a3);
                    a2 = __builtin_fmaf(f1.z, wv.z, a2);
                    a3 = __builtin_fmaf(f1.w, wv.w, a3);
                }
            }
            if (e < e1) {                           // odd tail
                const int i0 = E[e];
                const float4* __restrict__ fr0 =
                    reinterpret_cast<const float4*>(x + (size_t)i0 * C);
#pragma unroll
                for (int j = 0; j < NJ; ++j) {
                    const f32x4 wv = *reinterpret_cast<const f32x4*>(
                        &sW[buf][wbase + ((j ^ (lane & 7)) << 2)]);
                    const float4 f0 = fr0[j];
                    a0 = __builtin_fmaf(f0.x, wv.x, a0);
                    a1 = __builtin_fmaf(f0.y, wv.y, a1);
                    a2 = __builtin_fmaf(f0.z, wv.z, a2);
                    a3 = __builtin_fmaf(f0.w, wv.w, a3);
                }
            }
            acc0[ri] = a0; acc1[ri] = a1; acc2[ri] = a2; acc3[ri] = a3;
        }
        __syncthreads();   // staging(k+1) visible; buf free for k+2 overwrite
    }

    // epilogue: write rows + per-block BN partial stats
    float s = 0.f, ss = 0.f;
#pragma unroll
    for (int ri = 0; ri < RW; ++ri) {
        const int r = r0 + ri;
        if (r < n_out) {
            const float v = acc0[ri] + acc1[ri] + acc2[ri] + acc3[ri];
            y[(size_t)r * DCH + lane] = v;
            s += v;
            ss += v * v;
        }
    }
    red[0][wave][lane] = s;
    red[1][wave][lane] = ss;
    __syncthreads();
    if (tid < 64) {
        const float t = red[0][0][lane] + red[0][1][lane] + red[0][2][lane] + red[0][3][lane];
        unsafeAtomicAdd(&stats[lane], t);
    } else if (tid < 128) {
        const float t = red[1][0][lane] + red[1][1][lane] + red[1][2][lane] + red[1][3][lane];
        unsafeAtomicAdd(&stats[64 + lane], t);
    }
}

__global__ __launch_bounds__(256)
void bn_apply_kernel(float* __restrict__ x, int n_elem,
                     const float* __restrict__ stats,
                     const float* __restrict__ g,
                     const float* __restrict__ b,
                     float inv_n)
{
    const int d = threadIdx.x & 63;
    const float m   = stats[d] * inv_n;
    const float var = stats[64 + d] * inv_n - m * m;
    const float sc  = g[d] * rsqrtf(var + BN_EPS);
    const float sh  = b[d] - m * sc;
    for (int i = blockIdx.x * 256 + threadIdx.x; i < n_elem; i += gridDim.x * 256) {
        float v = x[i];
        x[i] = fmaxf(__builtin_fmaf(v, sc, sh), 0.f);
    }
}

__global__ __launch_bounds__(256)
void bn_final_kernel(float* __restrict__ y2, const float* __restrict__ xnet,
                     int n_elem,
                     const float* __restrict__ stats,
                     const float* __restrict__ g,
                     const float* __restrict__ b,
                     float inv_n)
{
    const int d = threadIdx.x & 63;
    const float m   = stats[d] * inv_n;
    const float var = stats[64 + d] * inv_n - m * m;
    const float sc  = g[d] * rsqrtf(var + BN_EPS);
    const float sh  = b[d] - m * sc;
    for (int i = blockIdx.x * 256 + threadIdx.x; i < n_elem; i += gridDim.x * 256) {
        float v = y2[i];
        y2[i] = xnet[i] + fmaxf(__builtin_fmaf(v, sc, sh), 0.f);
    }
}

extern "C" void kernel_launch(void* const* d_in, const int* in_sizes, int n_in,
                              void* d_out, int out_size, void* d_ws, size_t ws_size,
                              hipStream_t stream)
{
    const float* feats  = (const float*)d_in[0];
    const float* W_down = (const float*)d_in[1];
    const float* g0     = (const float*)d_in[2];
    const float* b0     = (const float*)d_in[3];
    const float* W1     = (const float*)d_in[4];
    const float* g1     = (const float*)d_in[5];
    const float* b1     = (const float*)d_in[6];
    const float* W2     = (const float*)d_in[7];
    const float* g2     = (const float*)d_in[8];
    const float* b2     = (const float*)d_in[9];
    const int* pdi      = (const int*)d_in[10];
    const int* pdo      = (const int*)d_in[11];
    const int* psi      = (const int*)d_in[12];
    const int* pso      = (const int*)d_in[13];

    const int P1     = in_sizes[10] / K_TAPS;
    const int P2     = in_sizes[12] / K_TAPS;
    const int M1     = in_sizes[10];
    const int n_out  = out_size / DCH;
    const int n_elem = n_out * DCH;
    const int NB     = n_out * K_TAPS;
    const float inv_n = 1.0f / (float)n_out;

    float* out = (float*)d_out;

    // ---- workspace layout (~30.5 MB, proven watermark) ----
    float* xnet  = (float*)d_ws;
    int*   counts = (int*)d_ws;          // overlays xnet during CSR builds
    float* stats = xnet + (size_t)n_elem;
    int* S = (int*)(stats + 384);
    int* E = S + (NB + 1);
    int* partials = E + M1;              // M1 >= M2
    float* Wt_dn = (float*)(partials + 1024);   // 27*64*32
    float* Wt_s1 = Wt_dn + 27 * 32 * DCH;       // 27*64*64
    float* Wt_s2 = Wt_s1 + 27 * DCH * DCH;      // 27*64*64

    float* st0 = stats;
    float* st1 = stats + 128;
    float* st2 = stats + 256;

    const dim3 blk(256);
    const dim3 gridH1((P1 + 255) / 256, K_TAPS);
    const dim3 gridH2((P2 + 255) / 256, K_TAPS);
    const int nchunks = (NB + SCAN_CHUNK - 1) / SCAN_CHUNK;
    const int ewBlocks = 2048;

    // down: C=32, RW=4 (16 rows/block) -> 3125 blocks
    constexpr int RW_DN = 4;
    const int gatherBlocksDn = (n_out + 4 * RW_DN - 1) / (4 * RW_DN);
    // subm: C=64, RW=8 (32 rows/block) -> 1563 blocks
    constexpr int RW_SM = 8;
    const int gatherBlocksSm = (n_out + 4 * RW_SM - 1) / (4 * RW_SM);

    hipMemsetAsync(stats, 0, sizeof(float) * 384, stream);

    // ---- merged W transposes ----
    transpose_w_kernel<<<81, blk, 0, stream>>>(W_down, W1, W2, Wt_dn, Wt_s1, Wt_s2);

    // ---- build down CSR ----
    hipMemsetAsync(counts, 0, sizeof(int) * (size_t)NB, stream);
    hist_kernel<<<gridH1, blk, 0, stream>>>(pdo, P1, counts);
    scan_sum_kernel<<<nchunks, blk, 0, stream>>>(counts, NB, partials);
    scan_partials_kernel<<<1, 512, 0, stream>>>(partials, nchunks);
    scan_write_kernel<<<nchunks, blk, 0, stream>>>(counts, NB, partials, S);
    fill_kernel<<<gridH1, blk, 0, stream>>>(pdi, pdo, P1, S, E);

    // ---- DownBlock: y0 = conv(feats) -> d_out (+stats) ; bnrelu in place ----
    gather_conv_kernel<32, RW_DN, 2><<<gatherBlocksDn, blk, 0, stream>>>(feats, Wt_dn, S, E, out, st0, n_out);
    bn_apply_kernel<<<ewBlocks, blk, 0, stream>>>(out, n_elem, st0, g0, b0, inv_n);

    // ---- rebuild CSR region as subm CSR (down CSR now dead) ----
    hipMemsetAsync(counts, 0, sizeof(int) * (size_t)NB, stream);
    hist_kernel<<<gridH2, blk, 0, stream>>>(pso, P2, counts);
    scan_sum_kernel<<<nchunks, blk, 0, stream>>>(counts, NB, partials);
    scan_partials_kernel<<<1, 512, 0, stream>>>(partials, nchunks);
    scan_write_kernel<<<nchunks, blk, 0, stream>>>(counts, NB, partials, S);
    fill_kernel<<<gridH2, blk, 0, stream>>>(psi, pso, P2, S, E);

    // ---- ResBlock conv1: y1 = conv(x0) -> xnet (+stats) ; bnrelu in place ----
    gather_conv_kernel<64, RW_SM, 2><<<gatherBlocksSm, blk, 0, stream>>>(out, Wt_s1, S, E, xnet, st1, n_out);
    bn_apply_kernel<<<ewBlocks, blk, 0, stream>>>(xnet, n_elem, st1, g1, b1, inv_n);

    // ---- ResBlock conv2: y2 = conv(x_net) -> d_out (+stats) ----
    gather_conv_kernel<64, RW_SM, 2><<<gatherBlocksSm, blk, 0, stream>>>(xnet, Wt_s2, S, E, out, st2, n_out);

    // ---- out = x_net + relu(bn(y2)) ----
    bn_final_kernel<<<ewBlocks, blk, 0, stream>>>(out, xnet, n_elem, st2, g2, b2, inv_n);
}

// Round 12
// 964.152 us; speedup vs baseline: 5.1599x; 3.1538x over previous
//
#include <hip/hip_runtime.h>
#include <hip/hip_bf16.h>

#define K_TAPS 27
#define DCH 64
#define BN_EPS 1e-5f
#define SCAN_CHUNK 4096

typedef float f32x4 __attribute__((ext_vector_type(4)));
typedef short bf16x8 __attribute__((ext_vector_type(8)));
typedef unsigned int uint;

// pack two f32 -> one dword of 2 bf16 (RNE). Used for BOTH A and B fragments,
// so any lo/hi ordering quirk cancels (same permutation on both operands).
#define CVTPK(dst, lo, hi) \
    asm("v_cvt_pk_bf16_f32 %0, %1, %2" : "=v"(dst) : "v"(lo), "v"(hi))

// ---------------------------------------------------------------------------
// CSR build: histogram over buckets b = orow*27 + k
// ---------------------------------------------------------------------------
__global__ __launch_bounds__(256)
void hist_kernel(const int* __restrict__ pout, int P, int* __restrict__ counts)
{
    const int k = blockIdx.y;
    const int p = blockIdx.x * 256 + threadIdx.x;
    if (p < P) {
        const int r = pout[(size_t)k * P + p];
        atomicAdd(&counts[r * K_TAPS + k], 1);
    }
}

__global__ __launch_bounds__(256)
void scan_sum_kernel(const int* __restrict__ counts, int n, int* __restrict__ partials)
{
    __shared__ int sm[256];
    const int base = blockIdx.x * SCAN_CHUNK;
    int s = 0;
#pragma unroll
    for (int j = 0; j < 16; ++j) {
        const int i = base + j * 256 + threadIdx.x;
        if (i < n) s += counts[i];
    }
    sm[threadIdx.x] = s;
    __syncthreads();
    for (int off = 128; off > 0; off >>= 1) {
        if (threadIdx.x < off) sm[threadIdx.x] += sm[threadIdx.x + off];
        __syncthreads();
    }
    if (threadIdx.x == 0) partials[blockIdx.x] = sm[0];
}

__global__ __launch_bounds__(512)
void scan_partials_kernel(int* __restrict__ partials, int n)
{
    __shared__ int sm[512];
    const int t = threadIdx.x;
    const int v = (t < n) ? partials[t] : 0;
    sm[t] = v;
    __syncthreads();
    for (int off = 1; off < 512; off <<= 1) {
        int tv = 0;
        if (t >= off) tv = sm[t - off];
        __syncthreads();
        if (t >= off) sm[t] += tv;
        __syncthreads();
    }
    if (t < n) partials[t] = sm[t] - v;  // exclusive
}

__global__ __launch_bounds__(256)
void scan_write_kernel(const int* __restrict__ counts, int n,
                       const int* __restrict__ chunkoff, int* __restrict__ S)
{
    __shared__ int sm[256];
    const int base = blockIdx.x * SCAN_CHUNK + threadIdx.x * 16;
    int v[16];
    int s = 0;
#pragma unroll
    for (int j = 0; j < 16; ++j) {
        const int i = base + j;
        v[j] = (i < n) ? counts[i] : 0;
        s += v[j];
    }
    sm[threadIdx.x] = s;
    __syncthreads();
    for (int off = 1; off < 256; off <<= 1) {
        int tv = 0;
        if (threadIdx.x >= off) tv = sm[threadIdx.x - off];
        __syncthreads();
        if (threadIdx.x >= off) sm[threadIdx.x] += tv;
        __syncthreads();
    }
    int run = chunkoff[blockIdx.x] + sm[threadIdx.x] - s;  // exclusive base
#pragma unroll
    for (int j = 0; j < 16; ++j) {
        const int i = base + j;
        if (i < n) S[i + 1] = run;
        run += v[j];
    }
    if (blockIdx.x == 0 && threadIdx.x == 0) S[0] = 0;
}

__global__ __launch_bounds__(256)
void fill_kernel(const int* __restrict__ pin, const int* __restrict__ pout, int P,
                 int* __restrict__ S, int* __restrict__ E)
{
    const int k = blockIdx.y;
    const int p = blockIdx.x * 256 + threadIdx.x;
    if (p < P) {
        const size_t i = (size_t)k * P + p;
        const int b = pout[i] * K_TAPS + k;
        const int pos = atomicAdd(&S[b + 1], 1);
        E[pos] = pin[i];
    }
}

// ---------------------------------------------------------------------------
// W pre-pack into MFMA B-fragment layout, bf16.
// For 16x16x32: lane l holds B[kb + (l>>4)*8 + j][nt*16 + (l&15)], j=0..7,
// packed pairwise with CVTPK (same instruction as the A-side pack).
// Wp[k][kc][nt][lane][4 dwords]. blocks 0..26 Wd(C=32), 27..53 W1, 54..80 W2.
// ---------------------------------------------------------------------------
__global__ __launch_bounds__(256)
void pack_w_kernel(const float* __restrict__ Wd,
                   const float* __restrict__ W1,
                   const float* __restrict__ W2,
                   uint* __restrict__ Pd, uint* __restrict__ P1, uint* __restrict__ P2)
{
    int b = blockIdx.x;
    const float* W; uint* P; int C, k;
    if (b < 27)      { W = Wd; P = Pd; C = 32; k = b; }
    else if (b < 54) { W = W1; P = P1; C = 64; k = b - 27; }
    else             { W = W2; P = P2; C = 64; k = b - 54; }
    const int KC = C / 32;
    for (int t = threadIdx.x; t < KC * 4 * 64; t += 256) {
        const int l  = t & 63;
        const int nt = (t >> 6) & 3;
        const int kc = t >> 8;
        const int c0  = kc * 32 + ((l >> 4) << 3);  // k-dim base for this lane
        const int col = nt * 16 + (l & 15);
        float f[8];
#pragma unroll
        for (int j = 0; j < 8; ++j)
            f[j] = W[((size_t)k * C + c0 + j) * DCH + col];
        uint4 u;
        CVTPK(u.x, f[0], f[1]);
        CVTPK(u.y, f[2], f[3]);
        CVTPK(u.z, f[4], f[5]);
        CVTPK(u.w, f[6], f[7]);
        *reinterpret_cast<uint4*>(P + ((size_t)((k * KC + kc) * 4 + nt) * 64 + l) * 4) = u;
    }
}

// ---------------------------------------------------------------------------
// Implicit-GEMM gather conv via v_mfma_f32_16x16x32_bf16.
//  - One wave per 16-row output tile (4 independent waves/block, no barriers).
//  - Per tap k: B-frags (W[k]) loaded once into 4*KC fragments, amortized
//    over all CSR entries of the tile -- kills the W-per-entry re-read that
//    bound r4-r10 at 300-1000us.
//  - Slot loop: lane's A-frag = fp32 source row of its output-row's s-th
//    entry, converted in-kernel via CVTPK; exhausted rows contribute zeros.
//  - C-frag layout (m89): col = lane&15, row = (lane>>4)*4 + reg.
//  - Fused BN partial stats via shfl-reduce + 8 atomics/wave.
// ---------------------------------------------------------------------------
template <int C>
__global__ __launch_bounds__(256, 4)
void mfma_conv_kernel(const float* __restrict__ x,
                      const uint* __restrict__ Wp,
                      const int* __restrict__ S,
                      const int* __restrict__ E,
                      float* __restrict__ y,
                      float* __restrict__ stats,
                      int n_out)
{
    constexpr int KC = C / 32;
    constexpr int SN = 16 * K_TAPS + 1;   // 433
    const int lane = threadIdx.x & 63;
    const int wave = threadIdx.x >> 6;
    const int r0 = blockIdx.x * 64 + wave * 16;
    if (r0 >= n_out) return;

    __shared__ int sS[4][SN];
    {
        const int base = r0 * K_TAPS;
        for (int i = lane; i < SN; i += 64) sS[wave][i] = S[base + i];
    }

    const int l15  = lane & 15;       // A-row within tile / D-column within ntile
    const int kgrp = lane >> 4;       // k-chunk group / D-row group
    const int koff = kgrp * 8;

    f32x4 acc[4];
#pragma unroll
    for (int nt = 0; nt < 4; ++nt) acc[nt] = (f32x4)0.f;

    for (int k = 0; k < K_TAPS; ++k) {
        // B fragments for this tap: KC x 4 ntiles, one dwordx4 per lane each
        bf16x8 B[KC][4];
#pragma unroll
        for (int kc = 0; kc < KC; ++kc)
#pragma unroll
            for (int nt = 0; nt < 4; ++nt)
                B[kc][nt] = *reinterpret_cast<const bf16x8*>(
                    Wp + ((size_t)((k * KC + kc) * 4 + nt) * 64 + lane) * 4);

        const int e0 = sS[wave][l15 * K_TAPS + k];
        const int e1 = sS[wave][l15 * K_TAPS + k + 1];
        int s = 0;
        while (__any(e0 + s < e1)) {
            const bool alive = (e0 + s < e1);
            const int irow = alive ? E[e0 + s] : 0;
            bf16x8 a[KC];
#pragma unroll
            for (int kc = 0; kc < KC; ++kc) {
                float4 f0 = {0.f, 0.f, 0.f, 0.f}, f1 = {0.f, 0.f, 0.f, 0.f};
                if (alive) {
                    const float4* fp = reinterpret_cast<const float4*>(
                        x + (size_t)irow * C + kc * 32 + koff);
                    f0 = fp[0];
                    f1 = fp[1];
                }
                uint4 u;
                CVTPK(u.x, f0.x, f0.y);
                CVTPK(u.y, f0.z, f0.w);
                CVTPK(u.z, f1.x, f1.y);
                CVTPK(u.w, f1.z, f1.w);
                a[kc] = *reinterpret_cast<bf16x8*>(&u);
            }
#pragma unroll
            for (int kc = 0; kc < KC; ++kc)
#pragma unroll
                for (int nt = 0; nt < 4; ++nt)
                    acc[nt] = __builtin_amdgcn_mfma_f32_16x16x32_bf16(
                        a[kc], B[kc][nt], acc[nt], 0, 0, 0);
            ++s;
        }
    }

    // epilogue: store rows + fused BN partial stats
#pragma unroll
    for (int nt = 0; nt < 4; ++nt) {
        const int col = nt * 16 + l15;
        float sum = 0.f, ssum = 0.f;
#pragma unroll
        for (int j = 0; j < 4; ++j) {
            const float v = acc[nt][j];
            y[(size_t)(r0 + kgrp * 4 + j) * DCH + col] = v;
            sum += v;
            ssum += v * v;
        }
        sum  += __shfl_xor(sum, 16);  sum  += __shfl_xor(sum, 32);
        ssum += __shfl_xor(ssum, 16); ssum += __shfl_xor(ssum, 32);
        if (kgrp == 0) {
            unsafeAtomicAdd(&stats[col], sum);
            unsafeAtomicAdd(&stats[64 + col], ssum);
        }
    }
}

__global__ __launch_bounds__(256)
void bn_apply_kernel(float* __restrict__ x, int n_elem,
                     const float* __restrict__ stats,
                     const float* __restrict__ g,
                     const float* __restrict__ b,
                     float inv_n)
{
    const int d = threadIdx.x & 63;
    const float m   = stats[d] * inv_n;
    const float var = stats[64 + d] * inv_n - m * m;
    const float sc  = g[d] * rsqrtf(var + BN_EPS);
    const float sh  = b[d] - m * sc;
    for (int i = blockIdx.x * 256 + threadIdx.x; i < n_elem; i += gridDim.x * 256) {
        float v = x[i];
        x[i] = fmaxf(__builtin_fmaf(v, sc, sh), 0.f);
    }
}

__global__ __launch_bounds__(256)
void bn_final_kernel(float* __restrict__ y2, const float* __restrict__ xnet,
                     int n_elem,
                     const float* __restrict__ stats,
                     const float* __restrict__ g,
                     const float* __restrict__ b,
                     float inv_n)
{
    const int d = threadIdx.x & 63;
    const float m   = stats[d] * inv_n;
    const float var = stats[64 + d] * inv_n - m * m;
    const float sc  = g[d] * rsqrtf(var + BN_EPS);
    const float sh  = b[d] - m * sc;
    for (int i = blockIdx.x * 256 + threadIdx.x; i < n_elem; i += gridDim.x * 256) {
        float v = y2[i];
        y2[i] = xnet[i] + fmaxf(__builtin_fmaf(v, sc, sh), 0.f);
    }
}

extern "C" void kernel_launch(void* const* d_in, const int* in_sizes, int n_in,
                              void* d_out, int out_size, void* d_ws, size_t ws_size,
                              hipStream_t stream)
{
    const float* feats  = (const float*)d_in[0];
    const float* W_down = (const float*)d_in[1];
    const float* g0     = (const float*)d_in[2];
    const float* b0     = (const float*)d_in[3];
    const float* W1     = (const float*)d_in[4];
    const float* g1     = (const float*)d_in[5];
    const float* b1     = (const float*)d_in[6];
    const float* W2     = (const float*)d_in[7];
    const float* g2     = (const float*)d_in[8];
    const float* b2     = (const float*)d_in[9];
    const int* pdi      = (const int*)d_in[10];
    const int* pdo      = (const int*)d_in[11];
    const int* psi      = (const int*)d_in[12];
    const int* pso      = (const int*)d_in[13];

    const int P1     = in_sizes[10] / K_TAPS;
    const int P2     = in_sizes[12] / K_TAPS;
    const int M1     = in_sizes[10];
    const int n_out  = out_size / DCH;
    const int n_elem = n_out * DCH;
    const int NB     = n_out * K_TAPS;
    const float inv_n = 1.0f / (float)n_out;

    float* out = (float*)d_out;

    // ---- workspace layout (~29.6 MB, under proven 30.5 watermark) ----
    float* xnet  = (float*)d_ws;
    int*   counts = (int*)d_ws;          // overlays xnet during CSR builds
    float* stats = xnet + (size_t)n_elem;
    int* S = (int*)(stats + 384);
    int* E = S + (NB + 1);
    int* partials = E + M1;              // M1 >= M2
    uint* Wp_dn = (uint*)(partials + 1024);     // 27*1*4*64*4 uints
    uint* Wp_s1 = Wp_dn + 27 * 1 * 4 * 64 * 4;  // 27*2*4*64*4
    uint* Wp_s2 = Wp_s1 + 27 * 2 * 4 * 64 * 4;

    float* st0 = stats;
    float* st1 = stats + 128;
    float* st2 = stats + 256;

    const dim3 blk(256);
    const dim3 gridH1((P1 + 255) / 256, K_TAPS);
    const dim3 gridH2((P2 + 255) / 256, K_TAPS);
    const int nchunks = (NB + SCAN_CHUNK - 1) / SCAN_CHUNK;
    const int ewBlocks = 2048;
    const int convBlocks = (n_out + 63) / 64;   // 64 rows/block (4 waves x 16)

    hipMemsetAsync(stats, 0, sizeof(float) * 384, stream);

    // ---- W fragment pre-pack (bf16, MFMA B layout) ----
    pack_w_kernel<<<81, blk, 0, stream>>>(W_down, W1, W2, Wp_dn, Wp_s1, Wp_s2);

    // ---- build down CSR ----
    hipMemsetAsync(counts, 0, sizeof(int) * (size_t)NB, stream);
    hist_kernel<<<gridH1, blk, 0, stream>>>(pdo, P1, counts);
    scan_sum_kernel<<<nchunks, blk, 0, stream>>>(counts, NB, partials);
    scan_partials_kernel<<<1, 512, 0, stream>>>(partials, nchunks);
    scan_write_kernel<<<nchunks, blk, 0, stream>>>(counts, NB, partials, S);
    fill_kernel<<<gridH1, blk, 0, stream>>>(pdi, pdo, P1, S, E);

    // ---- DownBlock: y0 = conv(feats) -> d_out (+stats) ; bnrelu in place ----
    mfma_conv_kernel<32><<<convBlocks, blk, 0, stream>>>(feats, Wp_dn, S, E, out, st0, n_out);
    bn_apply_kernel<<<ewBlocks, blk, 0, stream>>>(out, n_elem, st0, g0, b0, inv_n);

    // ---- rebuild CSR region as subm CSR (down CSR now dead) ----
    hipMemsetAsync(counts, 0, sizeof(int) * (size_t)NB, stream);
    hist_kernel<<<gridH2, blk, 0, stream>>>(pso, P2, counts);
    scan_sum_kernel<<<nchunks, blk, 0, stream>>>(counts, NB, partials);
    scan_partials_kernel<<<1, 512, 0, stream>>>(partials, nchunks);
    scan_write_kernel<<<nchunks, blk, 0, stream>>>(counts, NB, partials, S);
    fill_kernel<<<gridH2, blk, 0, stream>>>(psi, pso, P2, S, E);

    // ---- ResBlock conv1: y1 = conv(x0) -> xnet (+stats) ; bnrelu in place ----
    mfma_conv_kernel<64><<<convBlocks, blk, 0, stream>>>(out, Wp_s1, S, E, xnet, st1, n_out);
    bn_apply_kernel<<<ewBlocks, blk, 0, stream>>>(xnet, n_elem, st1, g1, b1, inv_n);

    // ---- ResBlock conv2: y2 = conv(x_net) -> d_out (+stats) ----
    mfma_conv_kernel<64><<<convBlocks, blk, 0, stream>>>(xnet, Wp_s2, S, E, out, st2, n_out);

    // ---- out = x_net + relu(bn(y2)) ----
    bn_final_kernel<<<ewBlocks, blk, 0, stream>>>(out, xnet, n_elem, st2, g2, b2, inv_n);
}

// Round 13
// 786.685 us; speedup vs baseline: 6.3239x; 1.2256x over previous
//
#include <hip/hip_runtime.h>
#include <hip/hip_bf16.h>

#define K_TAPS 27
#define DCH 64
#define BN_EPS 1e-5f
#define SCAN_CHUNK 4096

typedef float f32x4 __attribute__((ext_vector_type(4)));
typedef short bf16x8 __attribute__((ext_vector_type(8)));
typedef unsigned int uint;

// pack two f32 -> one dword of 2 bf16 (RNE). Used for BOTH A and B fragments,
// so any lo/hi ordering quirk cancels (same permutation on both operands).
#define CVTPK(dst, lo, hi) \
    asm("v_cvt_pk_bf16_f32 %0, %1, %2" : "=v"(dst) : "v"(lo), "v"(hi))

// ---------------------------------------------------------------------------
// CSR build pass A (fused hist+rank): returning atomic per pair, coalesced
// packed write: packed[i] = (bucket << 11) | rank_within_bucket.
// ---------------------------------------------------------------------------
__global__ __launch_bounds__(256)
void rank_kernel(const int* __restrict__ pout, int P,
                 int* __restrict__ counts, uint* __restrict__ packed)
{
    const int k = blockIdx.y;
    const int p = blockIdx.x * 256 + threadIdx.x;
    if (p < P) {
        const size_t i = (size_t)k * P + p;
        const int b = pout[i] * K_TAPS + k;
        const int r = atomicAdd(&counts[b], 1);
        packed[i] = ((uint)b << 11) | (uint)(r & 2047);
    }
}

// pass 1: per-chunk sums
__global__ __launch_bounds__(256)
void scan_sum_kernel(const int* __restrict__ counts, int n, int* __restrict__ partials)
{
    __shared__ int sm[256];
    const int base = blockIdx.x * SCAN_CHUNK;
    int s = 0;
#pragma unroll
    for (int j = 0; j < 16; ++j) {
        const int i = base + j * 256 + threadIdx.x;
        if (i < n) s += counts[i];
    }
    sm[threadIdx.x] = s;
    __syncthreads();
    for (int off = 128; off > 0; off >>= 1) {
        if (threadIdx.x < off) sm[threadIdx.x] += sm[threadIdx.x + off];
        __syncthreads();
    }
    if (threadIdx.x == 0) partials[blockIdx.x] = sm[0];
}

// pass 2: exclusive scan of chunk partials in place (single block)
__global__ __launch_bounds__(512)
void scan_partials_kernel(int* __restrict__ partials, int n)
{
    __shared__ int sm[512];
    const int t = threadIdx.x;
    const int v = (t < n) ? partials[t] : 0;
    sm[t] = v;
    __syncthreads();
    for (int off = 1; off < 512; off <<= 1) {
        int tv = 0;
        if (t >= off) tv = sm[t - off];
        __syncthreads();
        if (t >= off) sm[t] += tv;
        __syncthreads();
    }
    if (t < n) partials[t] = sm[t] - v;  // exclusive
}

// pass 3: S[i] = exclusive prefix (bucket start); S[n] = total.
__global__ __launch_bounds__(256)
void scan_write_kernel(const int* __restrict__ counts, int n,
                       const int* __restrict__ chunkoff, int* __restrict__ S)
{
    __shared__ int sm[256];
    const int base = blockIdx.x * SCAN_CHUNK + threadIdx.x * 16;
    int v[16];
    int s = 0;
#pragma unroll
    for (int j = 0; j < 16; ++j) {
        const int i = base + j;
        v[j] = (i < n) ? counts[i] : 0;
        s += v[j];
    }
    sm[threadIdx.x] = s;
    __syncthreads();
    for (int off = 1; off < 256; off <<= 1) {
        int tv = 0;
        if (threadIdx.x >= off) tv = sm[threadIdx.x - off];
        __syncthreads();
        if (threadIdx.x >= off) sm[threadIdx.x] += tv;
        __syncthreads();
    }
    int run = chunkoff[blockIdx.x] + sm[threadIdx.x] - s;  // exclusive base
#pragma unroll
    for (int j = 0; j < 16; ++j) {
        const int i = base + j;
        if (i < n) {
            S[i] = run;
            run += v[j];
            if (i == n - 1) S[n] = run;
        }
    }
}

// ---------------------------------------------------------------------------
// CSR build pass B (atomic-free scatter): E[S[b] + rank] = pin[i]
// ---------------------------------------------------------------------------
__global__ __launch_bounds__(256)
void scatter_kernel(const int* __restrict__ pin, const uint* __restrict__ packed,
                    int P, const int* __restrict__ S, int* __restrict__ E)
{
    const int k = blockIdx.y;
    const int p = blockIdx.x * 256 + threadIdx.x;
    if (p < P) {
        const size_t i = (size_t)k * P + p;
        const uint u = packed[i];
        E[S[u >> 11] + (int)(u & 2047u)] = pin[i];
    }
}

// ---------------------------------------------------------------------------
// W pre-pack into MFMA B-fragment layout, bf16 (CVTPK, same as A-side pack).
// Wp[k][kc][nt][lane][4 dwords]. blocks 0..26 Wd(C=32), 27..53 W1, 54..80 W2.
// ---------------------------------------------------------------------------
__global__ __launch_bounds__(256)
void pack_w_kernel(const float* __restrict__ Wd,
                   const float* __restrict__ W1,
                   const float* __restrict__ W2,
                   uint* __restrict__ Pd, uint* __restrict__ P1, uint* __restrict__ P2)
{
    int b = blockIdx.x;
    const float* W; uint* P; int C, k;
    if (b < 27)      { W = Wd; P = Pd; C = 32; k = b; }
    else if (b < 54) { W = W1; P = P1; C = 64; k = b - 27; }
    else             { W = W2; P = P2; C = 64; k = b - 54; }
    const int KC = C / 32;
    for (int t = threadIdx.x; t < KC * 4 * 64; t += 256) {
        const int l  = t & 63;
        const int nt = (t >> 6) & 3;
        const int kc = t >> 8;
        const int c0  = kc * 32 + ((l >> 4) << 3);  // k-dim base for this lane
        const int col = nt * 16 + (l & 15);
        float f[8];
#pragma unroll
        for (int j = 0; j < 8; ++j)
            f[j] = W[((size_t)k * C + c0 + j) * DCH + col];
        uint4 u;
        CVTPK(u.x, f[0], f[1]);
        CVTPK(u.y, f[2], f[3]);
        CVTPK(u.z, f[4], f[5]);
        CVTPK(u.w, f[6], f[7]);
        *reinterpret_cast<uint4*>(P + ((size_t)((k * KC + kc) * 4 + nt) * 64 + l) * 4) = u;
    }
}

// ---------------------------------------------------------------------------
// Implicit-GEMM gather conv via v_mfma_f32_16x16x32_bf16 (r12-proven).
// ---------------------------------------------------------------------------
template <int C>
__global__ __launch_bounds__(256, 4)
void mfma_conv_kernel(const float* __restrict__ x,
                      const uint* __restrict__ Wp,
                      const int* __restrict__ S,
                      const int* __restrict__ E,
                      float* __restrict__ y,
                      float* __restrict__ stats,
                      int n_out)
{
    constexpr int KC = C / 32;
    constexpr int SN = 16 * K_TAPS + 1;   // 433
    const int lane = threadIdx.x & 63;
    const int wave = threadIdx.x >> 6;
    const int r0 = blockIdx.x * 64 + wave * 16;
    if (r0 >= n_out) return;

    __shared__ int sS[4][SN];
    {
        const int base = r0 * K_TAPS;
        for (int i = lane; i < SN; i += 64) sS[wave][i] = S[base + i];
    }

    const int l15  = lane & 15;       // A-row within tile / D-column within ntile
    const int kgrp = lane >> 4;       // k-chunk group / D-row group
    const int koff = kgrp * 8;

    f32x4 acc[4];
#pragma unroll
    for (int nt = 0; nt < 4; ++nt) acc[nt] = (f32x4)0.f;

    for (int k = 0; k < K_TAPS; ++k) {
        // B fragments for this tap: KC x 4 ntiles, one dwordx4 per lane each
        bf16x8 B[KC][4];
#pragma unroll
        for (int kc = 0; kc < KC; ++kc)
#pragma unroll
            for (int nt = 0; nt < 4; ++nt)
                B[kc][nt] = *reinterpret_cast<const bf16x8*>(
                    Wp + ((size_t)((k * KC + kc) * 4 + nt) * 64 + lane) * 4);

        const int e0 = sS[wave][l15 * K_TAPS + k];
        const int e1 = sS[wave][l15 * K_TAPS + k + 1];
        int s = 0;
        while (__any(e0 + s < e1)) {
            const bool alive = (e0 + s < e1);
            const int irow = alive ? E[e0 + s] : 0;
            bf16x8 a[KC];
#pragma unroll
            for (int kc = 0; kc < KC; ++kc) {
                float4 f0 = {0.f, 0.f, 0.f, 0.f}, f1 = {0.f, 0.f, 0.f, 0.f};
                if (alive) {
                    const float4* fp = reinterpret_cast<const float4*>(
                        x + (size_t)irow * C + kc * 32 + koff);
                    f0 = fp[0];
                    f1 = fp[1];
                }
                uint4 u;
                CVTPK(u.x, f0.x, f0.y);
                CVTPK(u.y, f0.z, f0.w);
                CVTPK(u.z, f1.x, f1.y);
                CVTPK(u.w, f1.z, f1.w);
                a[kc] = *reinterpret_cast<bf16x8*>(&u);
            }
#pragma unroll
            for (int kc = 0; kc < KC; ++kc)
#pragma unroll
                for (int nt = 0; nt < 4; ++nt)
                    acc[nt] = __builtin_amdgcn_mfma_f32_16x16x32_bf16(
                        a[kc], B[kc][nt], acc[nt], 0, 0, 0);
            ++s;
        }
    }

    // epilogue: store rows + fused BN partial stats
#pragma unroll
    for (int nt = 0; nt < 4; ++nt) {
        const int col = nt * 16 + l15;
        float sum = 0.f, ssum = 0.f;
#pragma unroll
        for (int j = 0; j < 4; ++j) {
            const float v = acc[nt][j];
            y[(size_t)(r0 + kgrp * 4 + j) * DCH + col] = v;
            sum += v;
            ssum += v * v;
        }
        sum  += __shfl_xor(sum, 16);  sum  += __shfl_xor(sum, 32);
        ssum += __shfl_xor(ssum, 16); ssum += __shfl_xor(ssum, 32);
        if (kgrp == 0) {
            unsafeAtomicAdd(&stats[col], sum);
            unsafeAtomicAdd(&stats[64 + col], ssum);
        }
    }
}

__global__ __launch_bounds__(256)
void bn_apply_kernel(float* __restrict__ x, int n_elem,
                     const float* __restrict__ stats,
                     const float* __restrict__ g,
                     const float* __restrict__ b,
                     float inv_n)
{
    const int d = threadIdx.x & 63;
    const float m   = stats[d] * inv_n;
    const float var = stats[64 + d] * inv_n - m * m;
    const float sc  = g[d] * rsqrtf(var + BN_EPS);
    const float sh  = b[d] - m * sc;
    for (int i = blockIdx.x * 256 + threadIdx.x; i < n_elem; i += gridDim.x * 256) {
        float v = x[i];
        x[i] = fmaxf(__builtin_fmaf(v, sc, sh), 0.f);
    }
}

__global__ __launch_bounds__(256)
void bn_final_kernel(float* __restrict__ y2, const float* __restrict__ xnet,
                     int n_elem,
                     const float* __restrict__ stats,
                     const float* __restrict__ g,
                     const float* __restrict__ b,
                     float inv_n)
{
    const int d = threadIdx.x & 63;
    const float m   = stats[d] * inv_n;
    const float var = stats[64 + d] * inv_n - m * m;
    const float sc  = g[d] * rsqrtf(var + BN_EPS);
    const float sh  = b[d] - m * sc;
    for (int i = blockIdx.x * 256 + threadIdx.x; i < n_elem; i += gridDim.x * 256) {
        float v = y2[i];
        y2[i] = xnet[i] + fmaxf(__builtin_fmaf(v, sc, sh), 0.f);
    }
}

extern "C" void kernel_launch(void* const* d_in, const int* in_sizes, int n_in,
                              void* d_out, int out_size, void* d_ws, size_t ws_size,
                              hipStream_t stream)
{
    const float* feats  = (const float*)d_in[0];
    const float* W_down = (const float*)d_in[1];
    const float* g0     = (const float*)d_in[2];
    const float* b0     = (const float*)d_in[3];
    const float* W1     = (const float*)d_in[4];
    const float* g1     = (const float*)d_in[5];
    const float* b1     = (const float*)d_in[6];
    const float* W2     = (const float*)d_in[7];
    const float* g2     = (const float*)d_in[8];
    const float* b2     = (const float*)d_in[9];
    const int* pdi      = (const int*)d_in[10];
    const int* pdo      = (const int*)d_in[11];
    const int* psi      = (const int*)d_in[12];
    const int* pso      = (const int*)d_in[13];

    const int P1     = in_sizes[10] / K_TAPS;
    const int P2     = in_sizes[12] / K_TAPS;
    const int M1     = in_sizes[10];
    const int n_out  = out_size / DCH;
    const int n_elem = n_out * DCH;
    const int NB     = n_out * K_TAPS;
    const float inv_n = 1.0f / (float)n_out;

    float* out = (float*)d_out;

    // ---- workspace layout (~29.6 MB, r12-proven watermark) ----
    // xnet region doubles as: counts (NB ints) + rank_sm (M2 uints) during
    // CSR builds (xnet live only from ResBlock conv1 output onward).
    // d_out doubles as rank_dn (M1 uints) during the down build (live at conv1).
    float* xnet  = (float*)d_ws;
    int*   counts = (int*)d_ws;
    uint*  rank_sm = (uint*)d_ws + NB;
    float* stats = xnet + (size_t)n_elem;
    int* S = (int*)(stats + 384);
    int* E = S + (NB + 1);
    int* partials = E + M1;              // M1 >= M2
    uint* Wp_dn = (uint*)(partials + 1024);     // 27*1*4*64*4 uints
    uint* Wp_s1 = Wp_dn + 27 * 1 * 4 * 64 * 4;  // 27*2*4*64*4
    uint* Wp_s2 = Wp_s1 + 27 * 2 * 4 * 64 * 4;
    uint* rank_dn = (uint*)d_out;

    float* st0 = stats;
    float* st1 = stats + 128;
    float* st2 = stats + 256;

    const dim3 blk(256);
    const dim3 gridH1((P1 + 255) / 256, K_TAPS);
    const dim3 gridH2((P2 + 255) / 256, K_TAPS);
    const int nchunks = (NB + SCAN_CHUNK - 1) / SCAN_CHUNK;
    const int ewBlocks = 2048;
    const int convBlocks = (n_out + 63) / 64;   // 64 rows/block (4 waves x 16)

    hipMemsetAsync(stats, 0, sizeof(float) * 384, stream);

    // ---- W fragment pre-pack (bf16, MFMA B layout) ----
    pack_w_kernel<<<81, blk, 0, stream>>>(W_down, W1, W2, Wp_dn, Wp_s1, Wp_s2);

    // ---- build down CSR: rank pass -> scan -> scatter ----
    hipMemsetAsync(counts, 0, sizeof(int) * (size_t)NB, stream);
    rank_kernel<<<gridH1, blk, 0, stream>>>(pdo, P1, counts, rank_dn);
    scan_sum_kernel<<<nchunks, blk, 0, stream>>>(counts, NB, partials);
    scan_partials_kernel<<<1, 512, 0, stream>>>(partials, nchunks);
    scan_write_kernel<<<nchunks, blk, 0, stream>>>(counts, NB, partials, S);
    scatter_kernel<<<gridH1, blk, 0, stream>>>(pdi, rank_dn, P1, S, E);

    // ---- DownBlock: y0 = conv(feats) -> d_out (+stats) ; bnrelu in place ----
    mfma_conv_kernel<32><<<convBlocks, blk, 0, stream>>>(feats, Wp_dn, S, E, out, st0, n_out);
    bn_apply_kernel<<<ewBlocks, blk, 0, stream>>>(out, n_elem, st0, g0, b0, inv_n);

    // ---- build subm CSR in the same region (down CSR dead) ----
    hipMemsetAsync(counts, 0, sizeof(int) * (size_t)NB, stream);
    rank_kernel<<<gridH2, blk, 0, stream>>>(pso, P2, counts, rank_sm);
    scan_sum_kernel<<<nchunks, blk, 0, stream>>>(counts, NB, partials);
    scan_partials_kernel<<<1, 512, 0, stream>>>(partials, nchunks);
    scan_write_kernel<<<nchunks, blk, 0, stream>>>(counts, NB, partials, S);
    scatter_kernel<<<gridH2, blk, 0, stream>>>(psi, rank_sm, P2, S, E);

    // ---- ResBlock conv1: y1 = conv(x0) -> xnet (+stats) ; bnrelu in place ----
    mfma_conv_kernel<64><<<convBlocks, blk, 0, stream>>>(out, Wp_s1, S, E, xnet, st1, n_out);
    bn_apply_kernel<<<ewBlocks, blk, 0, stream>>>(xnet, n_elem, st1, g1, b1, inv_n);

    // ---- ResBlock conv2: y2 = conv(x_net) -> d_out (+stats) ----
    mfma_conv_kernel<64><<<convBlocks, blk, 0, stream>>>(xnet, Wp_s2, S, E, out, st2, n_out);

    // ---- out = x_net + relu(bn(y2)) ----
    bn_final_kernel<<<ewBlocks, blk, 0, stream>>>(out, xnet, n_elem, st2, g2, b2, inv_n);
}

// Round 14
// 687.809 us; speedup vs baseline: 7.2330x; 1.1438x over previous
//
#include <hip/hip_runtime.h>
#include <hip/hip_bf16.h>

#define K_TAPS 27
#define DCH 64
#define BN_EPS 1e-5f
#define SCAN_CHUNK 4096

typedef float f32x4 __attribute__((ext_vector_type(4)));
typedef short bf16x8 __attribute__((ext_vector_type(8)));
typedef unsigned int uint;
typedef unsigned short ushort;

// pack two f32 -> one dword of 2 bf16 (RNE); same instruction everywhere so
// rounding/order is consistent across pre-packed and in-kernel conversions.
#define CVTPK(dst, lo, hi) \
    asm("v_cvt_pk_bf16_f32 %0, %1, %2" : "=v"(dst) : "v"(lo), "v"(hi))

// ---------------------------------------------------------------------------
// CSR build pass A (fused hist+rank): returning atomic per pair, coalesced
// packed write: packed[i] = (bucket << 11) | rank_within_bucket.
// ---------------------------------------------------------------------------
__global__ __launch_bounds__(256)
void rank_kernel(const int* __restrict__ pout, int P,
                 int* __restrict__ counts, uint* __restrict__ packed)
{
    const int k = blockIdx.y;
    const int p = blockIdx.x * 256 + threadIdx.x;
    if (p < P) {
        const size_t i = (size_t)k * P + p;
        const int b = pout[i] * K_TAPS + k;
        const int r = atomicAdd(&counts[b], 1);
        packed[i] = ((uint)b << 11) | (uint)(r & 2047);
    }
}

__global__ __launch_bounds__(256)
void scan_sum_kernel(const int* __restrict__ counts, int n, int* __restrict__ partials)
{
    __shared__ int sm[256];
    const int base = blockIdx.x * SCAN_CHUNK;
    int s = 0;
#pragma unroll
    for (int j = 0; j < 16; ++j) {
        const int i = base + j * 256 + threadIdx.x;
        if (i < n) s += counts[i];
    }
    sm[threadIdx.x] = s;
    __syncthreads();
    for (int off = 128; off > 0; off >>= 1) {
        if (threadIdx.x < off) sm[threadIdx.x] += sm[threadIdx.x + off];
        __syncthreads();
    }
    if (threadIdx.x == 0) partials[blockIdx.x] = sm[0];
}

__global__ __launch_bounds__(512)
void scan_partials_kernel(int* __restrict__ partials, int n)
{
    __shared__ int sm[512];
    const int t = threadIdx.x;
    const int v = (t < n) ? partials[t] : 0;
    sm[t] = v;
    __syncthreads();
    for (int off = 1; off < 512; off <<= 1) {
        int tv = 0;
        if (t >= off) tv = sm[t - off];
        __syncthreads();
        if (t >= off) sm[t] += tv;
        __syncthreads();
    }
    if (t < n) partials[t] = sm[t] - v;  // exclusive
}

// S[i] = exclusive prefix (bucket start); S[n] = total.
__global__ __launch_bounds__(256)
void scan_write_kernel(const int* __restrict__ counts, int n,
                       const int* __restrict__ chunkoff, int* __restrict__ S)
{
    __shared__ int sm[256];
    const int base = blockIdx.x * SCAN_CHUNK + threadIdx.x * 16;
    int v[16];
    int s = 0;
#pragma unroll
    for (int j = 0; j < 16; ++j) {
        const int i = base + j;
        v[j] = (i < n) ? counts[i] : 0;
        s += v[j];
    }
    sm[threadIdx.x] = s;
    __syncthreads();
    for (int off = 1; off < 256; off <<= 1) {
        int tv = 0;
        if (threadIdx.x >= off) tv = sm[threadIdx.x - off];
        __syncthreads();
        if (threadIdx.x >= off) sm[threadIdx.x] += tv;
        __syncthreads();
    }
    int run = chunkoff[blockIdx.x] + sm[threadIdx.x] - s;  // exclusive base
#pragma unroll
    for (int j = 0; j < 16; ++j) {
        const int i = base + j;
        if (i < n) {
            S[i] = run;
            run += v[j];
            if (i == n - 1) S[n] = run;
        }
    }
}

// CSR build pass B (atomic-free scatter): E[S[b] + rank] = pin[i]
__global__ __launch_bounds__(256)
void scatter_kernel(const int* __restrict__ pin, const uint* __restrict__ packed,
                    int P, const int* __restrict__ S, int* __restrict__ E)
{
    const int k = blockIdx.y;
    const int p = blockIdx.x * 256 + threadIdx.x;
    if (p < P) {
        const size_t i = (size_t)k * P + p;
        const uint u = packed[i];
        E[S[u >> 11] + (int)(u & 2047u)] = pin[i];
    }
}

// ---------------------------------------------------------------------------
// W pre-pack into MFMA B-fragment layout, bf16 (CVTPK).
// Wp[k][kc][nt][lane][4 dwords]. blocks 0..26 Wd(C=32), 27..53 W1, 54..80 W2.
// ---------------------------------------------------------------------------
__global__ __launch_bounds__(256)
void pack_w_kernel(const float* __restrict__ Wd,
                   const float* __restrict__ W1,
                   const float* __restrict__ W2,
                   uint* __restrict__ Pd, uint* __restrict__ P1, uint* __restrict__ P2)
{
    int b = blockIdx.x;
    const float* W; uint* P; int C, k;
    if (b < 27)      { W = Wd; P = Pd; C = 32; k = b; }
    else if (b < 54) { W = W1; P = P1; C = 64; k = b - 27; }
    else             { W = W2; P = P2; C = 64; k = b - 54; }
    const int KC = C / 32;
    for (int t = threadIdx.x; t < KC * 4 * 64; t += 256) {
        const int l  = t & 63;
        const int nt = (t >> 6) & 3;
        const int kc = t >> 8;
        const int c0  = kc * 32 + ((l >> 4) << 3);
        const int col = nt * 16 + (l & 15);
        float f[8];
#pragma unroll
        for (int j = 0; j < 8; ++j)
            f[j] = W[((size_t)k * C + c0 + j) * DCH + col];
        uint4 u;
        CVTPK(u.x, f[0], f[1]);
        CVTPK(u.y, f[2], f[3]);
        CVTPK(u.z, f[4], f[5]);
        CVTPK(u.w, f[6], f[7]);
        *reinterpret_cast<uint4*>(P + ((size_t)((k * KC + kc) * 4 + nt) * 64 + l) * 4) = u;
    }
}

// fp32 -> packed bf16 (pairwise CVTPK, identical rounding to conv path)
__global__ __launch_bounds__(256)
void f2bf_kernel(const float* __restrict__ in, uint* __restrict__ out, int n_half)
{
    for (int i = blockIdx.x * 256 + threadIdx.x; i < n_half; i += gridDim.x * 256) {
        const float2 v = reinterpret_cast<const float2*>(in)[i];
        uint u;
        CVTPK(u, v.x, v.y);
        out[i] = u;
    }
}

// ---------------------------------------------------------------------------
// Implicit-GEMM gather conv, v2: 2-wave K-SPLIT blocks for occupancy.
//  - Block = 128 threads (2 waves) sharing ONE 16-row tile; wave w handles
//    taps k ≡ w (mod 2); partial C-frags reduced via 8KB LDS.
//    Grid 782 -> 3125 blocks: ~20 resident waves/CU vs r13's ~8.7.
//  - T=ushort: gather reads pre-converted bf16 rows (16B/lane/slot, half
//    the bytes of fp32) -- values bit-identical to the in-kernel CVTPK path.
//  - C-frag layout (m89): col = lane&15, row = (lane>>4)*4 + reg.
// ---------------------------------------------------------------------------
template <int C, typename T>
__global__ __launch_bounds__(128, 5)
void mfma_conv_kernel(const T* __restrict__ x,
                      const uint* __restrict__ Wp,
                      const int* __restrict__ S,
                      const int* __restrict__ E,
                      float* __restrict__ y,
                      float* __restrict__ stats,
                      int n_out)
{
    constexpr int KC = C / 32;
    constexpr int SN = 16 * K_TAPS + 1;   // 433
    const int tid  = threadIdx.x;
    const int lane = tid & 63;
    const int wave = tid >> 6;            // 0,1
    const int r0 = blockIdx.x * 16;
    if (r0 >= n_out) return;

    __shared__ int sS[SN];
    __shared__ f32x4 red[2][4][64];

    for (int i = tid; i < SN; i += 128) sS[i] = S[r0 * K_TAPS + i];
    __syncthreads();

    const int l15  = lane & 15;
    const int kgrp = lane >> 4;
    const int koff = kgrp * 8;

    f32x4 acc[4];
#pragma unroll
    for (int nt = 0; nt < 4; ++nt) acc[nt] = (f32x4)0.f;

    for (int k = wave; k < K_TAPS; k += 2) {
        bf16x8 B[KC][4];
#pragma unroll
        for (int kc = 0; kc < KC; ++kc)
#pragma unroll
            for (int nt = 0; nt < 4; ++nt)
                B[kc][nt] = *reinterpret_cast<const bf16x8*>(
                    Wp + ((size_t)((k * KC + kc) * 4 + nt) * 64 + lane) * 4);

        const int e0 = sS[l15 * K_TAPS + k];
        const int e1 = sS[l15 * K_TAPS + k + 1];
        int s = 0;
        while (__any(e0 + s < e1)) {
            const bool alive = (e0 + s < e1);
            const int irow = alive ? E[e0 + s] : 0;
            bf16x8 a[KC];
#pragma unroll
            for (int kc = 0; kc < KC; ++kc) {
                if constexpr (sizeof(T) == 2) {
                    bf16x8 av = (bf16x8)0;
                    if (alive)
                        av = *reinterpret_cast<const bf16x8*>(
                            (const ushort*)x + (size_t)irow * C + kc * 32 + koff);
                    a[kc] = av;
                } else {
                    float4 f0 = {0.f, 0.f, 0.f, 0.f}, f1 = {0.f, 0.f, 0.f, 0.f};
                    if (alive) {
                        const float4* fp = reinterpret_cast<const float4*>(
                            (const float*)x + (size_t)irow * C + kc * 32 + koff);
                        f0 = fp[0];
                        f1 = fp[1];
                    }
                    uint4 u;
                    CVTPK(u.x, f0.x, f0.y);
                    CVTPK(u.y, f0.z, f0.w);
                    CVTPK(u.z, f1.x, f1.y);
                    CVTPK(u.w, f1.z, f1.w);
                    a[kc] = *reinterpret_cast<bf16x8*>(&u);
                }
            }
#pragma unroll
            for (int kc = 0; kc < KC; ++kc)
#pragma unroll
                for (int nt = 0; nt < 4; ++nt)
                    acc[nt] = __builtin_amdgcn_mfma_f32_16x16x32_bf16(
                        a[kc], B[kc][nt], acc[nt], 0, 0, 0);
            ++s;
        }
    }

    // cross-wave reduce + epilogue (wave w handles ntiles 2w, 2w+1)
#pragma unroll
    for (int nt = 0; nt < 4; ++nt) red[wave][nt][lane] = acc[nt];
    __syncthreads();

#pragma unroll
    for (int t = 0; t < 2; ++t) {
        const int nt = wave * 2 + t;
        const f32x4 v4 = red[0][nt][lane] + red[1][nt][lane];
        const int col = nt * 16 + l15;
        float sum = 0.f, ssum = 0.f;
#pragma unroll
        for (int j = 0; j < 4; ++j) {
            const float v = v4[j];
            y[(size_t)(r0 + kgrp * 4 + j) * DCH + col] = v;
            sum += v;
            ssum += v * v;
        }
        sum  += __shfl_xor(sum, 16);  sum  += __shfl_xor(sum, 32);
        ssum += __shfl_xor(ssum, 16); ssum += __shfl_xor(ssum, 32);
        if (kgrp == 0) {
            unsafeAtomicAdd(&stats[col], sum);
            unsafeAtomicAdd(&stats[64 + col], ssum);
        }
    }
}

// BN+ReLU in place; optionally also emit packed-bf16 copy (CVTPK rounding).
template <bool WB>
__global__ __launch_bounds__(256)
void bn_apply_kernel(float* __restrict__ x, uint* __restrict__ xb, int n_half,
                     const float* __restrict__ stats,
                     const float* __restrict__ g,
                     const float* __restrict__ b,
                     float inv_n)
{
    const int d0 = (threadIdx.x * 2) & 63;
    const float m0 = stats[d0] * inv_n,     m1 = stats[d0 + 1] * inv_n;
    const float v0 = stats[64 + d0] * inv_n - m0 * m0;
    const float v1 = stats[64 + d0 + 1] * inv_n - m1 * m1;
    const float sc0 = g[d0] * rsqrtf(v0 + BN_EPS), sc1 = g[d0 + 1] * rsqrtf(v1 + BN_EPS);
    const float sh0 = b[d0] - m0 * sc0,            sh1 = b[d0 + 1] - m1 * sc1;
    for (int i = blockIdx.x * 256 + threadIdx.x; i < n_half; i += gridDim.x * 256) {
        float2 v = reinterpret_cast<float2*>(x)[i];
        const float r0 = fmaxf(__builtin_fmaf(v.x, sc0, sh0), 0.f);
        const float r1 = fmaxf(__builtin_fmaf(v.y, sc1, sh1), 0.f);
        reinterpret_cast<float2*>(x)[i] = make_float2(r0, r1);
        if (WB) {
            uint u;
            CVTPK(u, r0, r1);
            xb[i] = u;
        }
    }
}

__global__ __launch_bounds__(256)
void bn_final_kernel(float* __restrict__ y2, const float* __restrict__ xnet,
                     int n_elem,
                     const float* __restrict__ stats,
                     const float* __restrict__ g,
                     const float* __restrict__ b,
                     float inv_n)
{
    const int d = threadIdx.x & 63;
    const float m   = stats[d] * inv_n;
    const float var = stats[64 + d] * inv_n - m * m;
    const float sc  = g[d] * rsqrtf(var + BN_EPS);
    const float sh  = b[d] - m * sc;
    for (int i = blockIdx.x * 256 + threadIdx.x; i < n_elem; i += gridDim.x * 256) {
        float v = y2[i];
        y2[i] = xnet[i] + fmaxf(__builtin_fmaf(v, sc, sh), 0.f);
    }
}

extern "C" void kernel_launch(void* const* d_in, const int* in_sizes, int n_in,
                              void* d_out, int out_size, void* d_ws, size_t ws_size,
                              hipStream_t stream)
{
    const float* feats  = (const float*)d_in[0];
    const float* W_down = (const float*)d_in[1];
    const float* g0     = (const float*)d_in[2];
    const float* b0     = (const float*)d_in[3];
    const float* W1     = (const float*)d_in[4];
    const float* g1     = (const float*)d_in[5];
    const float* b1     = (const float*)d_in[6];
    const float* W2     = (const float*)d_in[7];
    const float* g2     = (const float*)d_in[8];
    const float* b2     = (const float*)d_in[9];
    const int* pdi      = (const int*)d_in[10];
    const int* pdo      = (const int*)d_in[11];
    const int* psi      = (const int*)d_in[12];
    const int* pso      = (const int*)d_in[13];

    const int P1     = in_sizes[10] / K_TAPS;
    const int P2     = in_sizes[12] / K_TAPS;
    const int M1     = in_sizes[10];
    const int Nin    = in_sizes[0] / 32;
    const int n_out  = out_size / DCH;
    const int n_elem = n_out * DCH;
    const int NB     = n_out * K_TAPS;
    const float inv_n = 1.0f / (float)n_out;

    float* out = (float*)d_out;

    // ---- workspace layout (base ~29.6 MB, r13-proven) ----
    float* xnet  = (float*)d_ws;
    int*   counts = (int*)d_ws;
    uint*  rank_sm = (uint*)d_ws + NB;
    float* stats = xnet + (size_t)n_elem;
    int* S = (int*)(stats + 384);
    int* E = S + (NB + 1);
    int* partials = E + M1;              // M1 >= M2
    uint* Wp_dn = (uint*)(partials + 1024);
    uint* Wp_s1 = Wp_dn + 27 * 1 * 4 * 64 * 4;
    uint* Wp_s2 = Wp_s1 + 27 * 2 * 4 * 64 * 4;
    uint* rank_dn = (uint*)d_out;

    // optional bf16-input extension (gated on ws_size)
    uintptr_t pa = (uintptr_t)(Wp_s2 + 27 * 2 * 4 * 64 * 4);
    pa = (pa + 15) & ~(uintptr_t)15;
    uint* featsb = (uint*)pa;                       // Nin*32 bf16 = Nin*16 uints
    uint* x0b    = featsb + (size_t)Nin * 16;       // n_elem/2 uints
    uint* xnetb  = x0b + (size_t)n_elem / 2;        // n_elem/2 uints
    const size_t needed = (size_t)((char*)(xnetb + n_elem / 2) - (char*)d_ws);
    const bool bf16path = ws_size >= needed;

    float* st0 = stats;
    float* st1 = stats + 128;
    float* st2 = stats + 256;

    const dim3 blk(256);
    const dim3 cblk(128);
    const dim3 gridH1((P1 + 255) / 256, K_TAPS);
    const dim3 gridH2((P2 + 255) / 256, K_TAPS);
    const int nchunks = (NB + SCAN_CHUNK - 1) / SCAN_CHUNK;
    const int ewBlocks = 2048;
    const int convBlocks = (n_out + 15) / 16;   // 16 rows/block, 2 waves k-split

    hipMemsetAsync(stats, 0, sizeof(float) * 384, stream);

    // ---- W fragment pre-pack ----
    pack_w_kernel<<<81, blk, 0, stream>>>(W_down, W1, W2, Wp_dn, Wp_s1, Wp_s2);
    if (bf16path)
        f2bf_kernel<<<ewBlocks, blk, 0, stream>>>(feats, featsb, Nin * 16);

    // ---- build down CSR: rank -> scan -> scatter ----
    hipMemsetAsync(counts, 0, sizeof(int) * (size_t)NB, stream);
    rank_kernel<<<gridH1, blk, 0, stream>>>(pdo, P1, counts, rank_dn);
    scan_sum_kernel<<<nchunks, blk, 0, stream>>>(counts, NB, partials);
    scan_partials_kernel<<<1, 512, 0, stream>>>(partials, nchunks);
    scan_write_kernel<<<nchunks, blk, 0, stream>>>(counts, NB, partials, S);
    scatter_kernel<<<gridH1, blk, 0, stream>>>(pdi, rank_dn, P1, S, E);

    // ---- DownBlock ----
    if (bf16path)
        mfma_conv_kernel<32, ushort><<<convBlocks, cblk, 0, stream>>>(
            (const ushort*)featsb, Wp_dn, S, E, out, st0, n_out);
    else
        mfma_conv_kernel<32, float><<<convBlocks, cblk, 0, stream>>>(
            feats, Wp_dn, S, E, out, st0, n_out);
    if (bf16path)
        bn_apply_kernel<true><<<ewBlocks, blk, 0, stream>>>(out, x0b, n_elem / 2, st0, g0, b0, inv_n);
    else
        bn_apply_kernel<false><<<ewBlocks, blk, 0, stream>>>(out, nullptr, n_elem / 2, st0, g0, b0, inv_n);

    // ---- build subm CSR (down CSR dead) ----
    hipMemsetAsync(counts, 0, sizeof(int) * (size_t)NB, stream);
    rank_kernel<<<gridH2, blk, 0, stream>>>(pso, P2, counts, rank_sm);
    scan_sum_kernel<<<nchunks, blk, 0, stream>>>(counts, NB, partials);
    scan_partials_kernel<<<1, 512, 0, stream>>>(partials, nchunks);
    scan_write_kernel<<<nchunks, blk, 0, stream>>>(counts, NB, partials, S);
    scatter_kernel<<<gridH2, blk, 0, stream>>>(psi, rank_sm, P2, S, E);

    // ---- ResBlock conv1 ----
    if (bf16path)
        mfma_conv_kernel<64, ushort><<<convBlocks, cblk, 0, stream>>>(
            (const ushort*)x0b, Wp_s1, S, E, xnet, st1, n_out);
    else
        mfma_conv_kernel<64, float><<<convBlocks, cblk, 0, stream>>>(
            out, Wp_s1, S, E, xnet, st1, n_out);
    if (bf16path)
        bn_apply_kernel<true><<<ewBlocks, blk, 0, stream>>>(xnet, xnetb, n_elem / 2, st1, g1, b1, inv_n);
    else
        bn_apply_kernel<false><<<ewBlocks, blk, 0, stream>>>(xnet, nullptr, n_elem / 2, st1, g1, b1, inv_n);

    // ---- ResBlock conv2 ----
    if (bf16path)
        mfma_conv_kernel<64, ushort><<<convBlocks, cblk, 0, stream>>>(
            (const ushort*)xnetb, Wp_s2, S, E, out, st2, n_out);
    else
        mfma_conv_kernel<64, float><<<convBlocks, cblk, 0, stream>>>(
            xnet, Wp_s2, S, E, out, st2, n_out);

    // ---- out = x_net + relu(bn(y2)) ----
    bn_final_kernel<<<ewBlocks, blk, 0, stream>>>(out, xnet, n_elem, st2, g2, b2, inv_n);
}

// Round 15
// 665.079 us; speedup vs baseline: 7.4802x; 1.0342x over previous
//
#include <hip/hip_runtime.h>
#include <hip/hip_bf16.h>

#define K_TAPS 27
#define DCH 64
#define BN_EPS 1e-5f
#define SCAN_CHUNK 4096

typedef float f32x4 __attribute__((ext_vector_type(4)));
typedef short bf16x8 __attribute__((ext_vector_type(8)));
typedef unsigned int uint;
typedef unsigned short ushort;

// pack two f32 -> one dword of 2 bf16 (RNE); same instruction everywhere so
// rounding/order is consistent across pre-packed and in-kernel conversions.
#define CVTPK(dst, lo, hi) \
    asm("v_cvt_pk_bf16_f32 %0, %1, %2" : "=v"(dst) : "v"(lo), "v"(hi))

// ---------------------------------------------------------------------------
// CSR build pass A (fused hist+rank): returning atomic per pair, coalesced
// packed write: packed[i] = (bucket << 11) | rank_within_bucket.
// ---------------------------------------------------------------------------
__global__ __launch_bounds__(256)
void rank_kernel(const int* __restrict__ pout, int P,
                 int* __restrict__ counts, uint* __restrict__ packed)
{
    const int k = blockIdx.y;
    const int p = blockIdx.x * 256 + threadIdx.x;
    if (p < P) {
        const size_t i = (size_t)k * P + p;
        const int b = pout[i] * K_TAPS + k;
        const int r = atomicAdd(&counts[b], 1);
        packed[i] = ((uint)b << 11) | (uint)(r & 2047);
    }
}

__global__ __launch_bounds__(256)
void scan_sum_kernel(const int* __restrict__ counts, int n, int* __restrict__ partials)
{
    __shared__ int sm[256];
    const int base = blockIdx.x * SCAN_CHUNK;
    int s = 0;
#pragma unroll
    for (int j = 0; j < 16; ++j) {
        const int i = base + j * 256 + threadIdx.x;
        if (i < n) s += counts[i];
    }
    sm[threadIdx.x] = s;
    __syncthreads();
    for (int off = 128; off > 0; off >>= 1) {
        if (threadIdx.x < off) sm[threadIdx.x] += sm[threadIdx.x + off];
        __syncthreads();
    }
    if (threadIdx.x == 0) partials[blockIdx.x] = sm[0];
}

__global__ __launch_bounds__(512)
void scan_partials_kernel(int* __restrict__ partials, int n)
{
    __shared__ int sm[512];
    const int t = threadIdx.x;
    const int v = (t < n) ? partials[t] : 0;
    sm[t] = v;
    __syncthreads();
    for (int off = 1; off < 512; off <<= 1) {
        int tv = 0;
        if (t >= off) tv = sm[t - off];
        __syncthreads();
        if (t >= off) sm[t] += tv;
        __syncthreads();
    }
    if (t < n) partials[t] = sm[t] - v;  // exclusive
}

// S[i] = exclusive prefix (bucket start); S[n] = total.
__global__ __launch_bounds__(256)
void scan_write_kernel(const int* __restrict__ counts, int n,
                       const int* __restrict__ chunkoff, int* __restrict__ S)
{
    __shared__ int sm[256];
    const int base = blockIdx.x * SCAN_CHUNK + threadIdx.x * 16;
    int v[16];
    int s = 0;
#pragma unroll
    for (int j = 0; j < 16; ++j) {
        const int i = base + j;
        v[j] = (i < n) ? counts[i] : 0;
        s += v[j];
    }
    sm[threadIdx.x] = s;
    __syncthreads();
    for (int off = 1; off < 256; off <<= 1) {
        int tv = 0;
        if (threadIdx.x >= off) tv = sm[threadIdx.x - off];
        __syncthreads();
        if (threadIdx.x >= off) sm[threadIdx.x] += tv;
        __syncthreads();
    }
    int run = chunkoff[blockIdx.x] + sm[threadIdx.x] - s;  // exclusive base
#pragma unroll
    for (int j = 0; j < 16; ++j) {
        const int i = base + j;
        if (i < n) {
            S[i] = run;
            run += v[j];
            if (i == n - 1) S[n] = run;
        }
    }
}

// CSR build pass B (atomic-free scatter): E[S[b] + rank] = pin[i]
__global__ __launch_bounds__(256)
void scatter_kernel(const int* __restrict__ pin, const uint* __restrict__ packed,
                    int P, const int* __restrict__ S, int* __restrict__ E)
{
    const int k = blockIdx.y;
    const int p = blockIdx.x * 256 + threadIdx.x;
    if (p < P) {
        const size_t i = (size_t)k * P + p;
        const uint u = packed[i];
        E[S[u >> 11] + (int)(u & 2047u)] = pin[i];
    }
}

// ---------------------------------------------------------------------------
// W pre-pack into MFMA B-fragment layout, bf16 (CVTPK).
// Wp[k][kc][nt][lane][4 dwords]. blocks 0..26 Wd(C=32), 27..53 W1, 54..80 W2.
// ---------------------------------------------------------------------------
__global__ __launch_bounds__(256)
void pack_w_kernel(const float* __restrict__ Wd,
                   const float* __restrict__ W1,
                   const float* __restrict__ W2,
                   uint* __restrict__ Pd, uint* __restrict__ P1, uint* __restrict__ P2)
{
    int b = blockIdx.x;
    const float* W; uint* P; int C, k;
    if (b < 27)      { W = Wd; P = Pd; C = 32; k = b; }
    else if (b < 54) { W = W1; P = P1; C = 64; k = b - 27; }
    else             { W = W2; P = P2; C = 64; k = b - 54; }
    const int KC = C / 32;
    for (int t = threadIdx.x; t < KC * 4 * 64; t += 256) {
        const int l  = t & 63;
        const int nt = (t >> 6) & 3;
        const int kc = t >> 8;
        const int c0  = kc * 32 + ((l >> 4) << 3);
        const int col = nt * 16 + (l & 15);
        float f[8];
#pragma unroll
        for (int j = 0; j < 8; ++j)
            f[j] = W[((size_t)k * C + c0 + j) * DCH + col];
        uint4 u;
        CVTPK(u.x, f[0], f[1]);
        CVTPK(u.y, f[2], f[3]);
        CVTPK(u.z, f[4], f[5]);
        CVTPK(u.w, f[6], f[7]);
        *reinterpret_cast<uint4*>(P + ((size_t)((k * KC + kc) * 4 + nt) * 64 + l) * 4) = u;
    }
}

// fp32 -> packed bf16 (pairwise CVTPK, identical rounding to conv path)
__global__ __launch_bounds__(256)
void f2bf_kernel(const float* __restrict__ in, uint* __restrict__ out, int n_half)
{
    for (int i = blockIdx.x * 256 + threadIdx.x; i < n_half; i += gridDim.x * 256) {
        const float2 v = reinterpret_cast<const float2*>(in)[i];
        uint u;
        CVTPK(u, v.x, v.y);
        out[i] = u;
    }
}

// ---------------------------------------------------------------------------
// Implicit-GEMM gather conv, v3: 2-wave k-split + slot-loop UNROLL-2.
//  - Two slots per iteration: both E loads and both row gathers issued
//    back-to-back (2 independent memory chains/wave in flight), then both
//    MFMA groups accumulate. Attacks the serial E->gather->MFMA chain that
//    left the r14 kernel gather-latency-bound at 1.5 TB/s effective.
//  - Structure otherwise identical to r14 (k%2 wave split, LDS reduce,
//    bf16 pre-converted inputs when ws allows, fused BN stats).
// ---------------------------------------------------------------------------
template <int C, typename T>
__global__ __launch_bounds__(128, 5)
void mfma_conv_kernel(const T* __restrict__ x,
                      const uint* __restrict__ Wp,
                      const int* __restrict__ S,
                      const int* __restrict__ E,
                      float* __restrict__ y,
                      float* __restrict__ stats,
                      int n_out)
{
    constexpr int KC = C / 32;
    constexpr int SN = 16 * K_TAPS + 1;   // 433
    const int tid  = threadIdx.x;
    const int lane = tid & 63;
    const int wave = tid >> 6;            // 0,1
    const int r0 = blockIdx.x * 16;
    if (r0 >= n_out) return;

    __shared__ int sS[SN];
    __shared__ f32x4 red[2][4][64];

    for (int i = tid; i < SN; i += 128) sS[i] = S[r0 * K_TAPS + i];
    __syncthreads();

    const int l15  = lane & 15;
    const int kgrp = lane >> 4;
    const int koff = kgrp * 8;

    f32x4 acc[4];
#pragma unroll
    for (int nt = 0; nt < 4; ++nt) acc[nt] = (f32x4)0.f;

    for (int k = wave; k < K_TAPS; k += 2) {
        bf16x8 B[KC][4];
#pragma unroll
        for (int kc = 0; kc < KC; ++kc)
#pragma unroll
            for (int nt = 0; nt < 4; ++nt)
                B[kc][nt] = *reinterpret_cast<const bf16x8*>(
                    Wp + ((size_t)((k * KC + kc) * 4 + nt) * 64 + lane) * 4);

        const int e1 = sS[l15 * K_TAPS + k + 1];
        for (int s = sS[l15 * K_TAPS + k]; ; s += 2) {
            const bool a0 = s < e1;
            const bool a1 = s + 1 < e1;
            if (!__any(a0)) break;
            // issue both E loads, then both gathers (2 chains in flight)
            const int ir0 = a0 ? E[s] : 0;
            const int ir1 = a1 ? E[s + 1] : 0;
            bf16x8 A0[KC], A1[KC];
#pragma unroll
            for (int kc = 0; kc < KC; ++kc) {
                if constexpr (sizeof(T) == 2) {
                    bf16x8 v0 = (bf16x8)0, v1 = (bf16x8)0;
                    if (a0) v0 = *reinterpret_cast<const bf16x8*>(
                        (const ushort*)x + (size_t)ir0 * C + kc * 32 + koff);
                    if (a1) v1 = *reinterpret_cast<const bf16x8*>(
                        (const ushort*)x + (size_t)ir1 * C + kc * 32 + koff);
                    A0[kc] = v0;
                    A1[kc] = v1;
                } else {
                    float4 f0 = {0.f, 0.f, 0.f, 0.f}, f1 = {0.f, 0.f, 0.f, 0.f};
                    float4 g0 = {0.f, 0.f, 0.f, 0.f}, g1 = {0.f, 0.f, 0.f, 0.f};
                    if (a0) {
                        const float4* fp = reinterpret_cast<const float4*>(
                            (const float*)x + (size_t)ir0 * C + kc * 32 + koff);
                        f0 = fp[0];
                        f1 = fp[1];
                    }
                    if (a1) {
                        const float4* gp = reinterpret_cast<const float4*>(
                            (const float*)x + (size_t)ir1 * C + kc * 32 + koff);
                        g0 = gp[0];
                        g1 = gp[1];
                    }
                    uint4 u, w;
                    CVTPK(u.x, f0.x, f0.y);
                    CVTPK(u.y, f0.z, f0.w);
                    CVTPK(u.z, f1.x, f1.y);
                    CVTPK(u.w, f1.z, f1.w);
                    CVTPK(w.x, g0.x, g0.y);
                    CVTPK(w.y, g0.z, g0.w);
                    CVTPK(w.z, g1.x, g1.y);
                    CVTPK(w.w, g1.z, g1.w);
                    A0[kc] = *reinterpret_cast<bf16x8*>(&u);
                    A1[kc] = *reinterpret_cast<bf16x8*>(&w);
                }
            }
#pragma unroll
            for (int kc = 0; kc < KC; ++kc)
#pragma unroll
                for (int nt = 0; nt < 4; ++nt)
                    acc[nt] = __builtin_amdgcn_mfma_f32_16x16x32_bf16(
                        A0[kc], B[kc][nt], acc[nt], 0, 0, 0);
#pragma unroll
            for (int kc = 0; kc < KC; ++kc)
#pragma unroll
                for (int nt = 0; nt < 4; ++nt)
                    acc[nt] = __builtin_amdgcn_mfma_f32_16x16x32_bf16(
                        A1[kc], B[kc][nt], acc[nt], 0, 0, 0);
        }
    }

    // cross-wave reduce + epilogue (wave w handles ntiles 2w, 2w+1)
#pragma unroll
    for (int nt = 0; nt < 4; ++nt) red[wave][nt][lane] = acc[nt];
    __syncthreads();

#pragma unroll
    for (int t = 0; t < 2; ++t) {
        const int nt = wave * 2 + t;
        const f32x4 v4 = red[0][nt][lane] + red[1][nt][lane];
        const int col = nt * 16 + l15;
        float sum = 0.f, ssum = 0.f;
#pragma unroll
        for (int j = 0; j < 4; ++j) {
            const float v = v4[j];
            y[(size_t)(r0 + kgrp * 4 + j) * DCH + col] = v;
            sum += v;
            ssum += v * v;
        }
        sum  += __shfl_xor(sum, 16);  sum  += __shfl_xor(sum, 32);
        ssum += __shfl_xor(ssum, 16); ssum += __shfl_xor(ssum, 32);
        if (kgrp == 0) {
            unsafeAtomicAdd(&stats[col], sum);
            unsafeAtomicAdd(&stats[64 + col], ssum);
        }
    }
}

// BN+ReLU in place; optionally also emit packed-bf16 copy (CVTPK rounding).
template <bool WB>
__global__ __launch_bounds__(256)
void bn_apply_kernel(float* __restrict__ x, uint* __restrict__ xb, int n_half,
                     const float* __restrict__ stats,
                     const float* __restrict__ g,
                     const float* __restrict__ b,
                     float inv_n)
{
    const int d0 = (threadIdx.x * 2) & 63;
    const float m0 = stats[d0] * inv_n,     m1 = stats[d0 + 1] * inv_n;
    const float v0 = stats[64 + d0] * inv_n - m0 * m0;
    const float v1 = stats[64 + d0 + 1] * inv_n - m1 * m1;
    const float sc0 = g[d0] * rsqrtf(v0 + BN_EPS), sc1 = g[d0 + 1] * rsqrtf(v1 + BN_EPS);
    const float sh0 = b[d0] - m0 * sc0,            sh1 = b[d0 + 1] - m1 * sc1;
    for (int i = blockIdx.x * 256 + threadIdx.x; i < n_half; i += gridDim.x * 256) {
        float2 v = reinterpret_cast<float2*>(x)[i];
        const float r0 = fmaxf(__builtin_fmaf(v.x, sc0, sh0), 0.f);
        const float r1 = fmaxf(__builtin_fmaf(v.y, sc1, sh1), 0.f);
        reinterpret_cast<float2*>(x)[i] = make_float2(r0, r1);
        if (WB) {
            uint u;
            CVTPK(u, r0, r1);
            xb[i] = u;
        }
    }
}

__global__ __launch_bounds__(256)
void bn_final_kernel(float* __restrict__ y2, const float* __restrict__ xnet,
                     int n_elem,
                     const float* __restrict__ stats,
                     const float* __restrict__ g,
                     const float* __restrict__ b,
                     float inv_n)
{
    const int d = threadIdx.x & 63;
    const float m   = stats[d] * inv_n;
    const float var = stats[64 + d] * inv_n - m * m;
    const float sc  = g[d] * rsqrtf(var + BN_EPS);
    const float sh  = b[d] - m * sc;
    for (int i = blockIdx.x * 256 + threadIdx.x; i < n_elem; i += gridDim.x * 256) {
        float v = y2[i];
        y2[i] = xnet[i] + fmaxf(__builtin_fmaf(v, sc, sh), 0.f);
    }
}

extern "C" void kernel_launch(void* const* d_in, const int* in_sizes, int n_in,
                              void* d_out, int out_size, void* d_ws, size_t ws_size,
                              hipStream_t stream)
{
    const float* feats  = (const float*)d_in[0];
    const float* W_down = (const float*)d_in[1];
    const float* g0     = (const float*)d_in[2];
    const float* b0     = (const float*)d_in[3];
    const float* W1     = (const float*)d_in[4];
    const float* g1     = (const float*)d_in[5];
    const float* b1     = (const float*)d_in[6];
    const float* W2     = (const float*)d_in[7];
    const float* g2     = (const float*)d_in[8];
    const float* b2     = (const float*)d_in[9];
    const int* pdi      = (const int*)d_in[10];
    const int* pdo      = (const int*)d_in[11];
    const int* psi      = (const int*)d_in[12];
    const int* pso      = (const int*)d_in[13];

    const int P1     = in_sizes[10] / K_TAPS;
    const int P2     = in_sizes[12] / K_TAPS;
    const int M1     = in_sizes[10];
    const int Nin    = in_sizes[0] / 32;
    const int n_out  = out_size / DCH;
    const int n_elem = n_out * DCH;
    const int NB     = n_out * K_TAPS;
    const float inv_n = 1.0f / (float)n_out;

    float* out = (float*)d_out;

    // ---- workspace layout (base ~29.6 MB, r13-proven) ----
    float* xnet  = (float*)d_ws;
    int*   counts = (int*)d_ws;
    uint*  rank_sm = (uint*)d_ws + NB;
    float* stats = xnet + (size_t)n_elem;
    int* S = (int*)(stats + 384);
    int* E = S + (NB + 1);
    int* partials = E + M1;              // M1 >= M2
    uint* Wp_dn = (uint*)(partials + 1024);
    uint* Wp_s1 = Wp_dn + 27 * 1 * 4 * 64 * 4;
    uint* Wp_s2 = Wp_s1 + 27 * 2 * 4 * 64 * 4;
    uint* rank_dn = (uint*)d_out;

    // optional bf16-input extension (gated on ws_size)
    uintptr_t pa = (uintptr_t)(Wp_s2 + 27 * 2 * 4 * 64 * 4);
    pa = (pa + 255) & ~(uintptr_t)255;
    uint* featsb = (uint*)pa;                       // Nin*32 bf16 = Nin*16 uints
    uint* x0b    = featsb + (size_t)Nin * 16;       // n_elem/2 uints
    uint* xnetb  = x0b + (size_t)n_elem / 2;        // n_elem/2 uints
    const size_t needed = (size_t)((char*)(xnetb + n_elem / 2) - (char*)d_ws);
    const bool bf16path = ws_size >= needed;

    float* st0 = stats;
    float* st1 = stats + 128;
    float* st2 = stats + 256;

    const dim3 blk(256);
    const dim3 cblk(128);
    const dim3 gridH1((P1 + 255) / 256, K_TAPS);
    const dim3 gridH2((P2 + 255) / 256, K_TAPS);
    const int nchunks = (NB + SCAN_CHUNK - 1) / SCAN_CHUNK;
    const int ewBlocks = 2048;
    const int convBlocks = (n_out + 15) / 16;   // 16 rows/block, 2 waves k-split

    hipMemsetAsync(stats, 0, sizeof(float) * 384, stream);

    // ---- W fragment pre-pack ----
    pack_w_kernel<<<81, blk, 0, stream>>>(W_down, W1, W2, Wp_dn, Wp_s1, Wp_s2);
    if (bf16path)
        f2bf_kernel<<<ewBlocks, blk, 0, stream>>>(feats, featsb, Nin * 16);

    // ---- build down CSR: rank -> scan -> scatter ----
    hipMemsetAsync(counts, 0, sizeof(int) * (size_t)NB, stream);
    rank_kernel<<<gridH1, blk, 0, stream>>>(pdo, P1, counts, rank_dn);
    scan_sum_kernel<<<nchunks, blk, 0, stream>>>(counts, NB, partials);
    scan_partials_kernel<<<1, 512, 0, stream>>>(partials, nchunks);
    scan_write_kernel<<<nchunks, blk, 0, stream>>>(counts, NB, partials, S);
    scatter_kernel<<<gridH1, blk, 0, stream>>>(pdi, rank_dn, P1, S, E);

    // ---- DownBlock ----
    if (bf16path)
        mfma_conv_kernel<32, ushort><<<convBlocks, cblk, 0, stream>>>(
            (const ushort*)featsb, Wp_dn, S, E, out, st0, n_out);
    else
        mfma_conv_kernel<32, float><<<convBlocks, cblk, 0, stream>>>(
            feats, Wp_dn, S, E, out, st0, n_out);
    if (bf16path)
        bn_apply_kernel<true><<<ewBlocks, blk, 0, stream>>>(out, x0b, n_elem / 2, st0, g0, b0, inv_n);
    else
        bn_apply_kernel<false><<<ewBlocks, blk, 0, stream>>>(out, nullptr, n_elem / 2, st0, g0, b0, inv_n);

    // ---- build subm CSR (down CSR dead) ----
    hipMemsetAsync(counts, 0, sizeof(int) * (size_t)NB, stream);
    rank_kernel<<<gridH2, blk, 0, stream>>>(pso, P2, counts, rank_sm);
    scan_sum_kernel<<<nchunks, blk, 0, stream>>>(counts, NB, partials);
    scan_partials_kernel<<<1, 512, 0, stream>>>(partials, nchunks);
    scan_write_kernel<<<nchunks, blk, 0, stream>>>(counts, NB, partials, S);
    scatter_kernel<<<gridH2, blk, 0, stream>>>(psi, rank_sm, P2, S, E);

    // ---- ResBlock conv1 ----
    if (bf16path)
        mfma_conv_kernel<64, ushort><<<convBlocks, cblk, 0, stream>>>(
            (const ushort*)x0b, Wp_s1, S, E, xnet, st1, n_out);
    else
        mfma_conv_kernel<64, float><<<convBlocks, cblk, 0, stream>>>(
            out, Wp_s1, S, E, xnet, st1, n_out);
    if (bf16path)
        bn_apply_kernel<true><<<ewBlocks, blk, 0, stream>>>(xnet, xnetb, n_elem / 2, st1, g1, b1, inv_n);
    else
        bn_apply_kernel<false><<<ewBlocks, blk, 0, stream>>>(xnet, nullptr, n_elem / 2, st1, g1, b1, inv_n);

    // ---- ResBlock conv2 ----
    if (bf16path)
        mfma_conv_kernel<64, ushort><<<convBlocks, cblk, 0, stream>>>(
            (const ushort*)xnetb, Wp_s2, S, E, out, st2, n_out);
    else
        mfma_conv_kernel<64, float><<<convBlocks, cblk, 0, stream>>>(
            xnet, Wp_s2, S, E, out, st2, n_out);

    // ---- out = x_net + relu(bn(y2)) ----
    bn_final_kernel<<<ewBlocks, blk, 0, stream>>>(out, xnet, n_elem, st2, g2, b2, inv_n);
}